// Round 1
// baseline (5943.715 us; speedup 1.0000x reference)
//
#include <hip/hip_runtime.h>

// ---------------------------------------------------------------------------
// GCN: 2x GraphConv (norm='both') + FC.   All fp32.
//   norm_out = rsqrt(max(deg_out,1)), norm_in = rsqrt(max(deg_in,1))
//   layer: h = (x * norm_out) @ W ; agg[dst] += h[src] ; out = agg*norm_in + b
// ---------------------------------------------------------------------------

__global__ void deg_kernel(const int* __restrict__ src, const int* __restrict__ dst,
                           int* __restrict__ deg_out, int* __restrict__ deg_in, int E) {
    int e = blockIdx.x * blockDim.x + threadIdx.x;
    if (e < E) {
        atomicAdd(&deg_out[src[e]], 1);
        atomicAdd(&deg_in[dst[e]], 1);
    }
}

__global__ void norm_kernel(const int* __restrict__ deg_out, const int* __restrict__ deg_in,
                            float* __restrict__ norm_out, float* __restrict__ norm_in, int n) {
    int i = blockIdx.x * blockDim.x + threadIdx.x;
    if (i < n) {
        int dg_o = deg_out[i]; if (dg_o < 1) dg_o = 1;
        int dg_i = deg_in[i];  if (dg_i < 1) dg_i = 1;
        norm_out[i] = rsqrtf((float)dg_o);
        norm_in[i]  = rsqrtf((float)dg_i);
    }
}

// Y[nrows x 128] = (X[nrows x 128] * scale[row]) @ W[128 x 128]
// block = 256 threads, 32 rows/block. Thread (r0 = tid/32, cg = tid%32) computes
// rows {r0, r0+8, r0+16, r0+24} x cols [4*cg .. 4*cg+3]  -> 16 FMA per W float4.
__global__ __launch_bounds__(256) void gemm128(
        const float* __restrict__ X, const float* __restrict__ scale,
        const float* __restrict__ W, float* __restrict__ Y, int nrows) {
    __shared__ float xs[32 * 128];   // 16 KB
    __shared__ float ws[128 * 128];  // 64 KB
    const int tid = threadIdx.x;
    const int base = blockIdx.x * 32;

    // stage W (4096 float4)
    for (int i = tid; i < 4096; i += 256) {
        *(float4*)(ws + i * 4) = *(const float4*)(W + i * 4);
    }
    // stage 32 scaled rows of X (1024 float4)
    for (int i = tid; i < 1024; i += 256) {
        int r  = i >> 5;
        int k4 = (i & 31) * 4;
        int gr = base + r;
        float4 v = make_float4(0.f, 0.f, 0.f, 0.f);
        if (gr < nrows) {
            v = *(const float4*)(X + (long long)gr * 128 + k4);
            float sc = scale[gr];
            v.x *= sc; v.y *= sc; v.z *= sc; v.w *= sc;
        }
        *(float4*)(xs + r * 128 + k4) = v;
    }
    __syncthreads();

    const int r0  = tid >> 5;        // 0..7
    const int col = (tid & 31) * 4;  // 0..124
    float4 a0 = make_float4(0.f,0.f,0.f,0.f);
    float4 a1 = a0, a2 = a0, a3 = a0;

    #pragma unroll 4
    for (int k = 0; k < 128; ++k) {
        float4 w = *(const float4*)(ws + k * 128 + col);
        float x0 = xs[(r0     ) * 128 + k];
        float x1 = xs[(r0 +  8) * 128 + k];
        float x2 = xs[(r0 + 16) * 128 + k];
        float x3 = xs[(r0 + 24) * 128 + k];
        a0.x += x0 * w.x; a0.y += x0 * w.y; a0.z += x0 * w.z; a0.w += x0 * w.w;
        a1.x += x1 * w.x; a1.y += x1 * w.y; a1.z += x1 * w.z; a1.w += x1 * w.w;
        a2.x += x2 * w.x; a2.y += x2 * w.y; a2.z += x2 * w.z; a2.w += x2 * w.w;
        a3.x += x3 * w.x; a3.y += x3 * w.y; a3.z += x3 * w.z; a3.w += x3 * w.w;
    }

    int gr;
    gr = base + r0;      if (gr < nrows) *(float4*)(Y + (long long)gr * 128 + col) = a0;
    gr = base + r0 + 8;  if (gr < nrows) *(float4*)(Y + (long long)gr * 128 + col) = a1;
    gr = base + r0 + 16; if (gr < nrows) *(float4*)(Y + (long long)gr * 128 + col) = a2;
    gr = base + r0 + 24; if (gr < nrows) *(float4*)(Y + (long long)gr * 128 + col) = a3;
}

// agg[dst[e]][:] += H[src[e]][:]   one thread per (edge, 4-float chunk)
__global__ void scatter_kernel(const float* __restrict__ H, const int* __restrict__ src,
                               const int* __restrict__ dst, float* __restrict__ agg, int E) {
    int idx = blockIdx.x * blockDim.x + threadIdx.x;
    if (idx >= E * 32) return;
    int e = idx >> 5;
    int c = (idx & 31) * 4;
    int s = src[e];
    int d = dst[e];
    float4 v = *(const float4*)(H + (long long)s * 128 + c);
    float* p = agg + (long long)d * 128 + c;
    atomicAdd(p + 0, v.x);
    atomicAdd(p + 1, v.y);
    atomicAdd(p + 2, v.z);
    atomicAdd(p + 3, v.w);
}

// buf = (relu?)(buf * norm_in[row] + b[col]) ; one thread per float4
__global__ void finalize_kernel(float* __restrict__ buf, const float* __restrict__ norm_in,
                                const float* __restrict__ b, int n, int do_relu) {
    int idx = blockIdx.x * blockDim.x + threadIdx.x;
    if (idx >= n * 32) return;
    int row = idx >> 5;
    int c   = (idx & 31) * 4;
    float ni = norm_in[row];
    float4 v = *(float4*)(buf + (long long)row * 128 + c);
    v.x = v.x * ni + b[c + 0];
    v.y = v.y * ni + b[c + 1];
    v.z = v.z * ni + b[c + 2];
    v.w = v.w * ni + b[c + 3];
    if (do_relu) {
        v.x = fmaxf(v.x, 0.f); v.y = fmaxf(v.y, 0.f);
        v.z = fmaxf(v.z, 0.f); v.w = fmaxf(v.w, 0.f);
    }
    *(float4*)(buf + (long long)row * 128 + c) = v;
}

// out[n x 40] = H[n x 128] @ Wfc[128 x 40] + bfc
__global__ void fc_kernel(const float* __restrict__ H, const float* __restrict__ Wfc,
                          const float* __restrict__ bfc, float* __restrict__ out, int n) {
    int idx = blockIdx.x * blockDim.x + threadIdx.x;
    if (idx >= n * 40) return;
    int row = idx / 40;
    int c   = idx - row * 40;
    const float* x = H + (long long)row * 128;
    float acc = bfc[c];
    #pragma unroll 8
    for (int k = 0; k < 128; ++k) acc += x[k] * Wfc[k * 40 + c];
    out[idx] = acc;
}

extern "C" void kernel_launch(void* const* d_in, const int* in_sizes, int n_in,
                              void* d_out, int out_size, void* d_ws, size_t ws_size,
                              hipStream_t stream) {
    const float* x   = (const float*)d_in[0];
    const int*   ei  = (const int*)  d_in[1];
    const float* W1  = (const float*)d_in[2];
    const float* b1  = (const float*)d_in[3];
    const float* W2  = (const float*)d_in[4];
    const float* b2  = (const float*)d_in[5];
    const float* Wfc = (const float*)d_in[6];
    const float* bfc = (const float*)d_in[7];
    float* out = (float*)d_out;

    const int N = in_sizes[0] / 128;
    const int E = in_sizes[1] / 2;
    const int* src = ei;
    const int* dst = ei + E;

    // workspace layout (all offsets 16B-aligned for N=100000)
    char* p = (char*)d_ws;
    float* norm_out = (float*)p; p += (size_t)N * 4;
    float* norm_in  = (float*)p; p += (size_t)N * 4;
    float* bufA     = (float*)p; p += (size_t)N * 128 * 4;
    float* bufB     = (float*)p; p += (size_t)N * 128 * 4;
    int*   deg_out  = (int*)p;   p += (size_t)N * 4;
    int*   deg_in   = (int*)p;   p += (size_t)N * 4;

    const int T = 256;
    // degrees + norms
    hipMemsetAsync(deg_out, 0, (size_t)N * 8, stream);  // deg_out+deg_in contiguous
    deg_kernel<<<(E + T - 1) / T, T, 0, stream>>>(src, dst, deg_out, deg_in, E);
    norm_kernel<<<(N + T - 1) / T, T, 0, stream>>>(deg_out, deg_in, norm_out, norm_in, N);

    const int gemm_grid    = (N + 31) / 32;
    const int scatter_grid = (E * 32 + T - 1) / T;
    const int elem_grid    = (N * 32 + T - 1) / T;

    // layer 0
    gemm128<<<gemm_grid, T, 0, stream>>>(x, norm_out, W1, bufA, N);
    hipMemsetAsync(bufB, 0, (size_t)N * 128 * 4, stream);
    scatter_kernel<<<scatter_grid, T, 0, stream>>>(bufA, src, dst, bufB, E);
    finalize_kernel<<<elem_grid, T, 0, stream>>>(bufB, norm_in, b1, N, 1);

    // layer 1
    gemm128<<<gemm_grid, T, 0, stream>>>(bufB, norm_out, W2, bufA, N);
    hipMemsetAsync(bufB, 0, (size_t)N * 128 * 4, stream);
    scatter_kernel<<<scatter_grid, T, 0, stream>>>(bufA, src, dst, bufB, E);
    finalize_kernel<<<elem_grid, T, 0, stream>>>(bufB, norm_in, b2, N, 0);

    // final FC
    fc_kernel<<<((size_t)N * 40 + T - 1) / T, T, 0, stream>>>(bufB, Wfc, bfc, out, N);
}

// Round 2
// 839.996 us; speedup vs baseline: 7.0759x; 7.0759x over previous
//
#include <hip/hip_runtime.h>

// ---------------------------------------------------------------------------
// GCN: 2x GraphConv (norm='both') + FC.  All fp32.
// R2: replace fp32 atomic scatter (2x2700us, atomic-RMW-bound, 4x write
// amplification) with device-built dst-CSR + register-accumulating gather.
// finalize (norm_in/bias/relu) fused into gather; big memsets dropped.
// ---------------------------------------------------------------------------

#define SCAN_BLK 1024   // elements per scan block

__global__ void deg_kernel(const int* __restrict__ src, const int* __restrict__ dst,
                           int* __restrict__ deg_out, int* __restrict__ deg_in, int E) {
    int e = blockIdx.x * blockDim.x + threadIdx.x;
    if (e < E) {
        atomicAdd(&deg_out[src[e]], 1);
        atomicAdd(&deg_in[dst[e]], 1);
    }
}

__global__ void norm_kernel(const int* __restrict__ deg_out, const int* __restrict__ deg_in,
                            float* __restrict__ norm_out, float* __restrict__ norm_in, int n) {
    int i = blockIdx.x * blockDim.x + threadIdx.x;
    if (i < n) {
        int dg_o = deg_out[i]; if (dg_o < 1) dg_o = 1;
        int dg_i = deg_in[i];  if (dg_i < 1) dg_i = 1;
        norm_out[i] = rsqrtf((float)dg_o);
        norm_in[i]  = rsqrtf((float)dg_i);
    }
}

// Exclusive scan of deg[] (n ints) into out[], block partial sums into aux[].
// 256 threads x 4 elements = 1024 per block.
__global__ __launch_bounds__(256) void scan_block_kernel(
        const int* __restrict__ deg, int* __restrict__ out, int* __restrict__ aux, int n) {
    __shared__ int sdata[256];
    const int tid = threadIdx.x;
    const int base = blockIdx.x * SCAN_BLK + tid * 4;
    int v0 = (base + 0 < n) ? deg[base + 0] : 0;
    int v1 = (base + 1 < n) ? deg[base + 1] : 0;
    int v2 = (base + 2 < n) ? deg[base + 2] : 0;
    int v3 = (base + 3 < n) ? deg[base + 3] : 0;
    int tot = v0 + v1 + v2 + v3;
    sdata[tid] = tot;
    __syncthreads();
    // Hillis-Steele inclusive scan over 256 thread totals
    for (int off = 1; off < 256; off <<= 1) {
        int t = (tid >= off) ? sdata[tid - off] : 0;
        __syncthreads();
        sdata[tid] += t;
        __syncthreads();
    }
    int excl = sdata[tid] - tot;
    if (base + 0 < n) out[base + 0] = excl;
    if (base + 1 < n) out[base + 1] = excl + v0;
    if (base + 2 < n) out[base + 2] = excl + v0 + v1;
    if (base + 3 < n) out[base + 3] = excl + v0 + v1 + v2;
    if (tid == 255) aux[blockIdx.x] = sdata[255];
}

// Exclusive scan of aux[nb] in place (single block; nb <= 1024).
__global__ __launch_bounds__(1024) void scan_aux_kernel(int* __restrict__ aux, int nb) {
    __shared__ int sdata[1024];
    const int tid = threadIdx.x;
    int v = (tid < nb) ? aux[tid] : 0;
    sdata[tid] = v;
    __syncthreads();
    for (int off = 1; off < 1024; off <<= 1) {
        int t = (tid >= off) ? sdata[tid - off] : 0;
        __syncthreads();
        sdata[tid] += t;
        __syncthreads();
    }
    if (tid < nb) aux[tid] = sdata[tid] - v;   // exclusive
}

// row_ptr[i] += aux[i/1024]; cursor[i] = row_ptr[i]
__global__ void add_offsets_kernel(int* __restrict__ row_ptr, const int* __restrict__ aux,
                                   int* __restrict__ cursor, int n) {
    int i = blockIdx.x * blockDim.x + threadIdx.x;
    if (i < n) {
        int r = row_ptr[i] + aux[i / SCAN_BLK];
        row_ptr[i] = r;
        cursor[i] = r;
    }
}

// csr_src[pos] = src[e], bucketed by dst
__global__ void fill_csr_kernel(const int* __restrict__ src, const int* __restrict__ dst,
                                int* __restrict__ cursor, int* __restrict__ csr_src, int E) {
    int e = blockIdx.x * blockDim.x + threadIdx.x;
    if (e < E) {
        int d = dst[e];
        int pos = atomicAdd(&cursor[d], 1);
        csr_src[pos] = src[e];
    }
}

// Y[nrows x 128] = (X[nrows x 128] * scale[row]) @ W[128 x 128]
__global__ __launch_bounds__(256) void gemm128(
        const float* __restrict__ X, const float* __restrict__ scale,
        const float* __restrict__ W, float* __restrict__ Y, int nrows) {
    __shared__ float xs[32 * 128];   // 16 KB
    __shared__ float ws[128 * 128];  // 64 KB
    const int tid = threadIdx.x;
    const int base = blockIdx.x * 32;

    for (int i = tid; i < 4096; i += 256) {
        *(float4*)(ws + i * 4) = *(const float4*)(W + i * 4);
    }
    for (int i = tid; i < 1024; i += 256) {
        int r  = i >> 5;
        int k4 = (i & 31) * 4;
        int gr = base + r;
        float4 v = make_float4(0.f, 0.f, 0.f, 0.f);
        if (gr < nrows) {
            v = *(const float4*)(X + (long long)gr * 128 + k4);
            float sc = scale[gr];
            v.x *= sc; v.y *= sc; v.z *= sc; v.w *= sc;
        }
        *(float4*)(xs + r * 128 + k4) = v;
    }
    __syncthreads();

    const int r0  = tid >> 5;
    const int col = (tid & 31) * 4;
    float4 a0 = make_float4(0.f,0.f,0.f,0.f);
    float4 a1 = a0, a2 = a0, a3 = a0;

    #pragma unroll 4
    for (int k = 0; k < 128; ++k) {
        float4 w = *(const float4*)(ws + k * 128 + col);
        float x0 = xs[(r0     ) * 128 + k];
        float x1 = xs[(r0 +  8) * 128 + k];
        float x2 = xs[(r0 + 16) * 128 + k];
        float x3 = xs[(r0 + 24) * 128 + k];
        a0.x += x0 * w.x; a0.y += x0 * w.y; a0.z += x0 * w.z; a0.w += x0 * w.w;
        a1.x += x1 * w.x; a1.y += x1 * w.y; a1.z += x1 * w.z; a1.w += x1 * w.w;
        a2.x += x2 * w.x; a2.y += x2 * w.y; a2.z += x2 * w.z; a2.w += x2 * w.w;
        a3.x += x3 * w.x; a3.y += x3 * w.y; a3.z += x3 * w.z; a3.w += x3 * w.w;
    }

    int gr;
    gr = base + r0;      if (gr < nrows) *(float4*)(Y + (long long)gr * 128 + col) = a0;
    gr = base + r0 + 8;  if (gr < nrows) *(float4*)(Y + (long long)gr * 128 + col) = a1;
    gr = base + r0 + 16; if (gr < nrows) *(float4*)(Y + (long long)gr * 128 + col) = a2;
    gr = base + r0 + 24; if (gr < nrows) *(float4*)(Y + (long long)gr * 128 + col) = a3;
}

// out[node] = relu?( (sum_{j in in(node)} H[csr_src[j]]) * norm_in[node] + b )
// 32 lanes per node (one float4/lane), 8 nodes per 256-thread block.
__global__ __launch_bounds__(256) void gather_kernel(
        const float* __restrict__ H, const int* __restrict__ row_ptr,
        const int* __restrict__ deg, const int* __restrict__ csr_src,
        const float* __restrict__ norm_in, const float* __restrict__ b,
        float* __restrict__ out, int n, int do_relu) {
    const int tid  = threadIdx.x;
    const int node = blockIdx.x * 8 + (tid >> 5);
    const int c    = (tid & 31) * 4;
    if (node >= n) return;

    const int start = row_ptr[node];
    const int cnt   = deg[node];
    float4 acc = make_float4(0.f, 0.f, 0.f, 0.f);

    int j = 0;
    // 2-deep unroll to keep two row loads in flight
    for (; j + 2 <= cnt; j += 2) {
        int s0 = csr_src[start + j];
        int s1 = csr_src[start + j + 1];
        float4 v0 = *(const float4*)(H + (long long)s0 * 128 + c);
        float4 v1 = *(const float4*)(H + (long long)s1 * 128 + c);
        acc.x += v0.x + v1.x; acc.y += v0.y + v1.y;
        acc.z += v0.z + v1.z; acc.w += v0.w + v1.w;
    }
    if (j < cnt) {
        int s0 = csr_src[start + j];
        float4 v0 = *(const float4*)(H + (long long)s0 * 128 + c);
        acc.x += v0.x; acc.y += v0.y; acc.z += v0.z; acc.w += v0.w;
    }

    float ni = norm_in[node];
    float4 bb = *(const float4*)(b + c);
    acc.x = acc.x * ni + bb.x;
    acc.y = acc.y * ni + bb.y;
    acc.z = acc.z * ni + bb.z;
    acc.w = acc.w * ni + bb.w;
    if (do_relu) {
        acc.x = fmaxf(acc.x, 0.f); acc.y = fmaxf(acc.y, 0.f);
        acc.z = fmaxf(acc.z, 0.f); acc.w = fmaxf(acc.w, 0.f);
    }
    *(float4*)(out + (long long)node * 128 + c) = acc;
}

// out[n x 40] = H[n x 128] @ Wfc[128 x 40] + bfc
__global__ void fc_kernel(const float* __restrict__ H, const float* __restrict__ Wfc,
                          const float* __restrict__ bfc, float* __restrict__ out, int n) {
    int idx = blockIdx.x * blockDim.x + threadIdx.x;
    if (idx >= n * 40) return;
    int row = idx / 40;
    int c   = idx - row * 40;
    const float* x = H + (long long)row * 128;
    float acc = bfc[c];
    #pragma unroll 8
    for (int k = 0; k < 128; ++k) acc += x[k] * Wfc[k * 40 + c];
    out[idx] = acc;
}

extern "C" void kernel_launch(void* const* d_in, const int* in_sizes, int n_in,
                              void* d_out, int out_size, void* d_ws, size_t ws_size,
                              hipStream_t stream) {
    const float* x   = (const float*)d_in[0];
    const int*   ei  = (const int*)  d_in[1];
    const float* W1  = (const float*)d_in[2];
    const float* b1  = (const float*)d_in[3];
    const float* W2  = (const float*)d_in[4];
    const float* b2  = (const float*)d_in[5];
    const float* Wfc = (const float*)d_in[6];
    const float* bfc = (const float*)d_in[7];
    float* out = (float*)d_out;

    const int N = in_sizes[0] / 128;
    const int E = in_sizes[1] / 2;
    const int* src = ei;
    const int* dst = ei + E;
    const int n_scan_blocks = (N + SCAN_BLK - 1) / SCAN_BLK;

    // workspace layout (N=100000 -> all 16B-aligned)
    char* p = (char*)d_ws;
    float* norm_out = (float*)p; p += (size_t)N * 4;
    float* norm_in  = (float*)p; p += (size_t)N * 4;
    float* bufA     = (float*)p; p += (size_t)N * 128 * 4;
    float* bufB     = (float*)p; p += (size_t)N * 128 * 4;
    int*   deg_out  = (int*)p;   p += (size_t)N * 4;
    int*   deg_in   = (int*)p;   p += (size_t)N * 4;
    int*   row_ptr  = (int*)p;   p += (size_t)N * 4;
    int*   cursor   = (int*)p;   p += (size_t)N * 4;
    int*   csr_src  = (int*)p;   p += (size_t)E * 4;
    int*   aux      = (int*)p;   p += (size_t)((n_scan_blocks + 3) & ~3) * 4;

    const int T = 256;

    // degrees + norms (deg_out, deg_in contiguous -> one memset)
    hipMemsetAsync(deg_out, 0, (size_t)N * 8, stream);
    deg_kernel<<<(E + T - 1) / T, T, 0, stream>>>(src, dst, deg_out, deg_in, E);
    norm_kernel<<<(N + T - 1) / T, T, 0, stream>>>(deg_out, deg_in, norm_out, norm_in, N);

    // CSR build: exclusive scan of deg_in -> row_ptr; bucket-fill csr_src
    scan_block_kernel<<<n_scan_blocks, 256, 0, stream>>>(deg_in, row_ptr, aux, N);
    scan_aux_kernel<<<1, 1024, 0, stream>>>(aux, n_scan_blocks);
    add_offsets_kernel<<<(N + T - 1) / T, T, 0, stream>>>(row_ptr, aux, cursor, N);
    fill_csr_kernel<<<(E + T - 1) / T, T, 0, stream>>>(src, dst, cursor, csr_src, E);

    const int gemm_grid   = (N + 31) / 32;
    const int gather_grid = (N + 7) / 8;

    // layer 0
    gemm128<<<gemm_grid, T, 0, stream>>>(x, norm_out, W1, bufA, N);
    gather_kernel<<<gather_grid, T, 0, stream>>>(bufA, row_ptr, deg_in, csr_src,
                                                 norm_in, b1, bufB, N, 1);
    // layer 1
    gemm128<<<gemm_grid, T, 0, stream>>>(bufB, norm_out, W2, bufA, N);
    gather_kernel<<<gather_grid, T, 0, stream>>>(bufA, row_ptr, deg_in, csr_src,
                                                 norm_in, b2, bufB, N, 0);

    // final FC
    fc_kernel<<<((size_t)N * 40 + T - 1) / T, T, 0, stream>>>(bufB, Wfc, bfc, out, N);
}

// Round 3
// 782.445 us; speedup vs baseline: 7.5963x; 1.0736x over previous
//
#include <hip/hip_runtime.h>

// ---------------------------------------------------------------------------
// GCN: 2x GraphConv (norm='both') + FC.  All fp32.
// R2: CSR gather instead of atomic scatter (5943 -> 840 us).
// R3: fc_kernel rewritten (LDS-staged Wfc, 4 rows x 1 col per thread,
//     was 139 us load-issue-bound); gather inner loop unrolled 4-deep.
// ---------------------------------------------------------------------------

#define SCAN_BLK 1024   // elements per scan block

__global__ void deg_kernel(const int* __restrict__ src, const int* __restrict__ dst,
                           int* __restrict__ deg_out, int* __restrict__ deg_in, int E) {
    int e = blockIdx.x * blockDim.x + threadIdx.x;
    if (e < E) {
        atomicAdd(&deg_out[src[e]], 1);
        atomicAdd(&deg_in[dst[e]], 1);
    }
}

__global__ void norm_kernel(const int* __restrict__ deg_out, const int* __restrict__ deg_in,
                            float* __restrict__ norm_out, float* __restrict__ norm_in, int n) {
    int i = blockIdx.x * blockDim.x + threadIdx.x;
    if (i < n) {
        int dg_o = deg_out[i]; if (dg_o < 1) dg_o = 1;
        int dg_i = deg_in[i];  if (dg_i < 1) dg_i = 1;
        norm_out[i] = rsqrtf((float)dg_o);
        norm_in[i]  = rsqrtf((float)dg_i);
    }
}

// Exclusive scan of deg[] (n ints) into out[], block partial sums into aux[].
__global__ __launch_bounds__(256) void scan_block_kernel(
        const int* __restrict__ deg, int* __restrict__ out, int* __restrict__ aux, int n) {
    __shared__ int sdata[256];
    const int tid = threadIdx.x;
    const int base = blockIdx.x * SCAN_BLK + tid * 4;
    int v0 = (base + 0 < n) ? deg[base + 0] : 0;
    int v1 = (base + 1 < n) ? deg[base + 1] : 0;
    int v2 = (base + 2 < n) ? deg[base + 2] : 0;
    int v3 = (base + 3 < n) ? deg[base + 3] : 0;
    int tot = v0 + v1 + v2 + v3;
    sdata[tid] = tot;
    __syncthreads();
    for (int off = 1; off < 256; off <<= 1) {
        int t = (tid >= off) ? sdata[tid - off] : 0;
        __syncthreads();
        sdata[tid] += t;
        __syncthreads();
    }
    int excl = sdata[tid] - tot;
    if (base + 0 < n) out[base + 0] = excl;
    if (base + 1 < n) out[base + 1] = excl + v0;
    if (base + 2 < n) out[base + 2] = excl + v0 + v1;
    if (base + 3 < n) out[base + 3] = excl + v0 + v1 + v2;
    if (tid == 255) aux[blockIdx.x] = sdata[255];
}

__global__ __launch_bounds__(1024) void scan_aux_kernel(int* __restrict__ aux, int nb) {
    __shared__ int sdata[1024];
    const int tid = threadIdx.x;
    int v = (tid < nb) ? aux[tid] : 0;
    sdata[tid] = v;
    __syncthreads();
    for (int off = 1; off < 1024; off <<= 1) {
        int t = (tid >= off) ? sdata[tid - off] : 0;
        __syncthreads();
        sdata[tid] += t;
        __syncthreads();
    }
    if (tid < nb) aux[tid] = sdata[tid] - v;   // exclusive
}

__global__ void add_offsets_kernel(int* __restrict__ row_ptr, const int* __restrict__ aux,
                                   int* __restrict__ cursor, int n) {
    int i = blockIdx.x * blockDim.x + threadIdx.x;
    if (i < n) {
        int r = row_ptr[i] + aux[i / SCAN_BLK];
        row_ptr[i] = r;
        cursor[i] = r;
    }
}

__global__ void fill_csr_kernel(const int* __restrict__ src, const int* __restrict__ dst,
                                int* __restrict__ cursor, int* __restrict__ csr_src, int E) {
    int e = blockIdx.x * blockDim.x + threadIdx.x;
    if (e < E) {
        int d = dst[e];
        int pos = atomicAdd(&cursor[d], 1);
        csr_src[pos] = src[e];
    }
}

// Y[nrows x 128] = (X[nrows x 128] * scale[row]) @ W[128 x 128]
__global__ __launch_bounds__(256) void gemm128(
        const float* __restrict__ X, const float* __restrict__ scale,
        const float* __restrict__ W, float* __restrict__ Y, int nrows) {
    __shared__ float xs[32 * 128];   // 16 KB
    __shared__ float ws[128 * 128];  // 64 KB
    const int tid = threadIdx.x;
    const int base = blockIdx.x * 32;

    for (int i = tid; i < 4096; i += 256) {
        *(float4*)(ws + i * 4) = *(const float4*)(W + i * 4);
    }
    for (int i = tid; i < 1024; i += 256) {
        int r  = i >> 5;
        int k4 = (i & 31) * 4;
        int gr = base + r;
        float4 v = make_float4(0.f, 0.f, 0.f, 0.f);
        if (gr < nrows) {
            v = *(const float4*)(X + (long long)gr * 128 + k4);
            float sc = scale[gr];
            v.x *= sc; v.y *= sc; v.z *= sc; v.w *= sc;
        }
        *(float4*)(xs + r * 128 + k4) = v;
    }
    __syncthreads();

    const int r0  = tid >> 5;
    const int col = (tid & 31) * 4;
    float4 a0 = make_float4(0.f,0.f,0.f,0.f);
    float4 a1 = a0, a2 = a0, a3 = a0;

    #pragma unroll 4
    for (int k = 0; k < 128; ++k) {
        float4 w = *(const float4*)(ws + k * 128 + col);
        float x0 = xs[(r0     ) * 128 + k];
        float x1 = xs[(r0 +  8) * 128 + k];
        float x2 = xs[(r0 + 16) * 128 + k];
        float x3 = xs[(r0 + 24) * 128 + k];
        a0.x += x0 * w.x; a0.y += x0 * w.y; a0.z += x0 * w.z; a0.w += x0 * w.w;
        a1.x += x1 * w.x; a1.y += x1 * w.y; a1.z += x1 * w.z; a1.w += x1 * w.w;
        a2.x += x2 * w.x; a2.y += x2 * w.y; a2.z += x2 * w.z; a2.w += x2 * w.w;
        a3.x += x3 * w.x; a3.y += x3 * w.y; a3.z += x3 * w.z; a3.w += x3 * w.w;
    }

    int gr;
    gr = base + r0;      if (gr < nrows) *(float4*)(Y + (long long)gr * 128 + col) = a0;
    gr = base + r0 + 8;  if (gr < nrows) *(float4*)(Y + (long long)gr * 128 + col) = a1;
    gr = base + r0 + 16; if (gr < nrows) *(float4*)(Y + (long long)gr * 128 + col) = a2;
    gr = base + r0 + 24; if (gr < nrows) *(float4*)(Y + (long long)gr * 128 + col) = a3;
}

// out[node] = relu?( (sum_{j in in(node)} H[csr_src[j]]) * norm_in[node] + b )
// 32 lanes per node (one float4/lane), 8 nodes per 256-thread block.
__global__ __launch_bounds__(256) void gather_kernel(
        const float* __restrict__ H, const int* __restrict__ row_ptr,
        const int* __restrict__ deg, const int* __restrict__ csr_src,
        const float* __restrict__ norm_in, const float* __restrict__ b,
        float* __restrict__ out, int n, int do_relu) {
    const int tid  = threadIdx.x;
    const int node = blockIdx.x * 8 + (tid >> 5);
    const int c    = (tid & 31) * 4;
    if (node >= n) return;

    const int start = row_ptr[node];
    const int cnt   = deg[node];
    float4 acc = make_float4(0.f, 0.f, 0.f, 0.f);

    int j = 0;
    // 4-deep unroll: 4 independent row loads in flight (L3-latency hiding)
    for (; j + 4 <= cnt; j += 4) {
        int s0 = csr_src[start + j];
        int s1 = csr_src[start + j + 1];
        int s2 = csr_src[start + j + 2];
        int s3 = csr_src[start + j + 3];
        float4 v0 = *(const float4*)(H + (long long)s0 * 128 + c);
        float4 v1 = *(const float4*)(H + (long long)s1 * 128 + c);
        float4 v2 = *(const float4*)(H + (long long)s2 * 128 + c);
        float4 v3 = *(const float4*)(H + (long long)s3 * 128 + c);
        acc.x += (v0.x + v1.x) + (v2.x + v3.x);
        acc.y += (v0.y + v1.y) + (v2.y + v3.y);
        acc.z += (v0.z + v1.z) + (v2.z + v3.z);
        acc.w += (v0.w + v1.w) + (v2.w + v3.w);
    }
    for (; j < cnt; ++j) {
        int s0 = csr_src[start + j];
        float4 v0 = *(const float4*)(H + (long long)s0 * 128 + c);
        acc.x += v0.x; acc.y += v0.y; acc.z += v0.z; acc.w += v0.w;
    }

    float ni = norm_in[node];
    float4 bb = *(const float4*)(b + c);
    acc.x = acc.x * ni + bb.x;
    acc.y = acc.y * ni + bb.y;
    acc.z = acc.z * ni + bb.z;
    acc.w = acc.w * ni + bb.w;
    if (do_relu) {
        acc.x = fmaxf(acc.x, 0.f); acc.y = fmaxf(acc.y, 0.f);
        acc.z = fmaxf(acc.z, 0.f); acc.w = fmaxf(acc.w, 0.f);
    }
    *(float4*)(out + (long long)node * 128 + c) = acc;
}

// out[n x 40] = H[n x 128] @ Wfc[128 x 40] + bfc
// LDS-staged Wfc; each thread: 4 rows x 1 col -> 16 FMA per 4 global float4
// loads (wave-broadcast: 40 threads of a row-group share addresses).
__global__ __launch_bounds__(256) void fc_kernel(
        const float* __restrict__ H, const float* __restrict__ Wfc,
        const float* __restrict__ bfc, float* __restrict__ out, int n) {
    __shared__ float ws[128 * 40];   // 20 KB
    const int tid = threadIdx.x;
    for (int i = tid; i < 1280; i += 256) {
        *(float4*)(ws + i * 4) = *(const float4*)(Wfc + i * 4);
    }
    __syncthreads();

    const int idx = blockIdx.x * 256 + tid;
    const int rg  = idx / 40;         // row group of 4
    const int c   = idx - rg * 40;
    const int r0  = rg * 4;
    if (r0 >= n) return;

    const float* h = H + (long long)r0 * 128;
    float bb = bfc[c];

    if (r0 + 4 <= n) {
        float a0 = 0.f, a1 = 0.f, a2 = 0.f, a3 = 0.f;
        #pragma unroll 4
        for (int k = 0; k < 128; k += 4) {
            float4 x0 = *(const float4*)(h + k);
            float4 x1 = *(const float4*)(h + 128 + k);
            float4 x2 = *(const float4*)(h + 256 + k);
            float4 x3 = *(const float4*)(h + 384 + k);
            float w0 = ws[(k + 0) * 40 + c];
            float w1 = ws[(k + 1) * 40 + c];
            float w2 = ws[(k + 2) * 40 + c];
            float w3 = ws[(k + 3) * 40 + c];
            a0 += x0.x * w0 + x0.y * w1 + x0.z * w2 + x0.w * w3;
            a1 += x1.x * w0 + x1.y * w1 + x1.z * w2 + x1.w * w3;
            a2 += x2.x * w0 + x2.y * w1 + x2.z * w2 + x2.w * w3;
            a3 += x3.x * w0 + x3.y * w1 + x3.z * w2 + x3.w * w3;
        }
        out[(long long)(r0 + 0) * 40 + c] = a0 + bb;
        out[(long long)(r0 + 1) * 40 + c] = a1 + bb;
        out[(long long)(r0 + 2) * 40 + c] = a2 + bb;
        out[(long long)(r0 + 3) * 40 + c] = a3 + bb;
    } else {
        for (int r = r0; r < n; ++r) {
            const float* hr = H + (long long)r * 128;
            float a = 0.f;
            #pragma unroll 4
            for (int k = 0; k < 128; k += 4) {
                float4 x = *(const float4*)(hr + k);
                a += x.x * ws[(k + 0) * 40 + c] + x.y * ws[(k + 1) * 40 + c]
                   + x.z * ws[(k + 2) * 40 + c] + x.w * ws[(k + 3) * 40 + c];
            }
            out[(long long)r * 40 + c] = a + bb;
        }
    }
}

extern "C" void kernel_launch(void* const* d_in, const int* in_sizes, int n_in,
                              void* d_out, int out_size, void* d_ws, size_t ws_size,
                              hipStream_t stream) {
    const float* x   = (const float*)d_in[0];
    const int*   ei  = (const int*)  d_in[1];
    const float* W1  = (const float*)d_in[2];
    const float* b1  = (const float*)d_in[3];
    const float* W2  = (const float*)d_in[4];
    const float* b2  = (const float*)d_in[5];
    const float* Wfc = (const float*)d_in[6];
    const float* bfc = (const float*)d_in[7];
    float* out = (float*)d_out;

    const int N = in_sizes[0] / 128;
    const int E = in_sizes[1] / 2;
    const int* src = ei;
    const int* dst = ei + E;
    const int n_scan_blocks = (N + SCAN_BLK - 1) / SCAN_BLK;

    char* p = (char*)d_ws;
    float* norm_out = (float*)p; p += (size_t)N * 4;
    float* norm_in  = (float*)p; p += (size_t)N * 4;
    float* bufA     = (float*)p; p += (size_t)N * 128 * 4;
    float* bufB     = (float*)p; p += (size_t)N * 128 * 4;
    int*   deg_out  = (int*)p;   p += (size_t)N * 4;
    int*   deg_in   = (int*)p;   p += (size_t)N * 4;
    int*   row_ptr  = (int*)p;   p += (size_t)N * 4;
    int*   cursor   = (int*)p;   p += (size_t)N * 4;
    int*   csr_src  = (int*)p;   p += (size_t)E * 4;
    int*   aux      = (int*)p;   p += (size_t)((n_scan_blocks + 3) & ~3) * 4;

    const int T = 256;

    hipMemsetAsync(deg_out, 0, (size_t)N * 8, stream);
    deg_kernel<<<(E + T - 1) / T, T, 0, stream>>>(src, dst, deg_out, deg_in, E);
    norm_kernel<<<(N + T - 1) / T, T, 0, stream>>>(deg_out, deg_in, norm_out, norm_in, N);

    scan_block_kernel<<<n_scan_blocks, 256, 0, stream>>>(deg_in, row_ptr, aux, N);
    scan_aux_kernel<<<1, 1024, 0, stream>>>(aux, n_scan_blocks);
    add_offsets_kernel<<<(N + T - 1) / T, T, 0, stream>>>(row_ptr, aux, cursor, N);
    fill_csr_kernel<<<(E + T - 1) / T, T, 0, stream>>>(src, dst, cursor, csr_src, E);

    const int gemm_grid   = (N + 31) / 32;
    const int gather_grid = (N + 7) / 8;

    // layer 0
    gemm128<<<gemm_grid, T, 0, stream>>>(x, norm_out, W1, bufA, N);
    gather_kernel<<<gather_grid, T, 0, stream>>>(bufA, row_ptr, deg_in, csr_src,
                                                 norm_in, b1, bufB, N, 1);
    // layer 1
    gemm128<<<gemm_grid, T, 0, stream>>>(bufB, norm_out, W2, bufA, N);
    gather_kernel<<<gather_grid, T, 0, stream>>>(bufA, row_ptr, deg_in, csr_src,
                                                 norm_in, b2, bufB, N, 0);

    // final FC
    const int fc_grid = ((N + 3) / 4 * 40 + T - 1) / T;
    fc_kernel<<<fc_grid, T, 0, stream>>>(bufB, Wfc, bfc, out, N);
}

// Round 4
// 584.757 us; speedup vs baseline: 10.1644x; 1.3381x over previous
//
#include <hip/hip_runtime.h>

// ---------------------------------------------------------------------------
// GCN: 2x GraphConv (norm='both') + FC.  All fp32.
// R2: CSR gather instead of atomic scatter (5943 -> 840 us).
// R3: LDS-staged fc, gather unroll-4 (840 -> 782 us).
// R4: (a) atomic-free CSR fill: rank[e] comes free from the degree-count
//         atomic; fill becomes a plain store (was 130 us, 105 MB HBM write
//         from 1.6M atomics x 64B).
//     (b) fold layer2+FC: out = segsum((h1*no)@(W2@Wfc))*ni + (b2@Wfc+bfc).
//         Layer-2 GEMM is 128x40, second gather moves 40 floats/row, fc gone.
// ---------------------------------------------------------------------------

#define SCAN_BLK 1024   // elements per scan block

// degree count; the deg_in atomic's return value is the edge's stable rank
// within its dst bucket -> csr fill needs no atomics.
__global__ void deg_kernel(const int* __restrict__ src, const int* __restrict__ dst,
                           int* __restrict__ deg_out, int* __restrict__ deg_in,
                           int* __restrict__ rank, int E) {
    int e = blockIdx.x * blockDim.x + threadIdx.x;
    if (e < E) {
        atomicAdd(&deg_out[src[e]], 1);
        rank[e] = atomicAdd(&deg_in[dst[e]], 1);
    }
}

__global__ void norm_kernel(const int* __restrict__ deg_out, const int* __restrict__ deg_in,
                            float* __restrict__ norm_out, float* __restrict__ norm_in, int n) {
    int i = blockIdx.x * blockDim.x + threadIdx.x;
    if (i < n) {
        int dg_o = deg_out[i]; if (dg_o < 1) dg_o = 1;
        int dg_i = deg_in[i];  if (dg_i < 1) dg_i = 1;
        norm_out[i] = rsqrtf((float)dg_o);
        norm_in[i]  = rsqrtf((float)dg_i);
    }
}

// Exclusive scan of deg[] (n ints) into out[], block partial sums into aux[].
__global__ __launch_bounds__(256) void scan_block_kernel(
        const int* __restrict__ deg, int* __restrict__ out, int* __restrict__ aux, int n) {
    __shared__ int sdata[256];
    const int tid = threadIdx.x;
    const int base = blockIdx.x * SCAN_BLK + tid * 4;
    int v0 = (base + 0 < n) ? deg[base + 0] : 0;
    int v1 = (base + 1 < n) ? deg[base + 1] : 0;
    int v2 = (base + 2 < n) ? deg[base + 2] : 0;
    int v3 = (base + 3 < n) ? deg[base + 3] : 0;
    int tot = v0 + v1 + v2 + v3;
    sdata[tid] = tot;
    __syncthreads();
    for (int off = 1; off < 256; off <<= 1) {
        int t = (tid >= off) ? sdata[tid - off] : 0;
        __syncthreads();
        sdata[tid] += t;
        __syncthreads();
    }
    int excl = sdata[tid] - tot;
    if (base + 0 < n) out[base + 0] = excl;
    if (base + 1 < n) out[base + 1] = excl + v0;
    if (base + 2 < n) out[base + 2] = excl + v0 + v1;
    if (base + 3 < n) out[base + 3] = excl + v0 + v1 + v2;
    if (tid == 255) aux[blockIdx.x] = sdata[255];
}

__global__ __launch_bounds__(1024) void scan_aux_kernel(int* __restrict__ aux, int nb) {
    __shared__ int sdata[1024];
    const int tid = threadIdx.x;
    int v = (tid < nb) ? aux[tid] : 0;
    sdata[tid] = v;
    __syncthreads();
    for (int off = 1; off < 1024; off <<= 1) {
        int t = (tid >= off) ? sdata[tid - off] : 0;
        __syncthreads();
        sdata[tid] += t;
        __syncthreads();
    }
    if (tid < nb) aux[tid] = sdata[tid] - v;   // exclusive
}

__global__ void add_offsets_kernel(int* __restrict__ row_ptr, const int* __restrict__ aux, int n) {
    int i = blockIdx.x * blockDim.x + threadIdx.x;
    if (i < n) row_ptr[i] += aux[i / SCAN_BLK];
}

// atomic-free bucket fill: pos is unique by construction
__global__ void fill_csr_kernel(const int* __restrict__ src, const int* __restrict__ dst,
                                const int* __restrict__ rank, const int* __restrict__ row_ptr,
                                int* __restrict__ csr_src, int E) {
    int e = blockIdx.x * blockDim.x + threadIdx.x;
    if (e < E) {
        int pos = row_ptr[dst[e]] + rank[e];
        csr_src[pos] = src[e];
    }
}

// W2p[128x40] = W2[128x128] @ Wfc[128x40];  b2p[40] = b2 @ Wfc + bfc
__global__ void fold_w2_kernel(const float* __restrict__ W2, const float* __restrict__ Wfc,
                               const float* __restrict__ b2, const float* __restrict__ bfc,
                               float* __restrict__ W2p, float* __restrict__ b2p) {
    int idx = blockIdx.x * blockDim.x + threadIdx.x;
    if (idx < 128 * 40) {
        int k = idx / 40, c = idx - (idx / 40) * 40;
        const float* w2row = W2 + k * 128;
        float a = 0.f;
        #pragma unroll 8
        for (int j = 0; j < 128; ++j) a += w2row[j] * Wfc[j * 40 + c];
        W2p[idx] = a;
    } else if (idx < 129 * 40) {
        int c = idx - 128 * 40;
        float a = bfc[c];
        #pragma unroll 8
        for (int j = 0; j < 128; ++j) a += b2[j] * Wfc[j * 40 + c];
        b2p[c] = a;
    }
}

// Y[nrows x 128] = (X[nrows x 128] * scale[row]) @ W[128 x 128]
__global__ __launch_bounds__(256) void gemm128(
        const float* __restrict__ X, const float* __restrict__ scale,
        const float* __restrict__ W, float* __restrict__ Y, int nrows) {
    __shared__ float xs[32 * 128];   // 16 KB
    __shared__ float ws[128 * 128];  // 64 KB
    const int tid = threadIdx.x;
    const int base = blockIdx.x * 32;

    for (int i = tid; i < 4096; i += 256) {
        *(float4*)(ws + i * 4) = *(const float4*)(W + i * 4);
    }
    for (int i = tid; i < 1024; i += 256) {
        int r  = i >> 5;
        int k4 = (i & 31) * 4;
        int gr = base + r;
        float4 v = make_float4(0.f, 0.f, 0.f, 0.f);
        if (gr < nrows) {
            v = *(const float4*)(X + (long long)gr * 128 + k4);
            float sc = scale[gr];
            v.x *= sc; v.y *= sc; v.z *= sc; v.w *= sc;
        }
        *(float4*)(xs + r * 128 + k4) = v;
    }
    __syncthreads();

    const int r0  = tid >> 5;
    const int col = (tid & 31) * 4;
    float4 a0 = make_float4(0.f,0.f,0.f,0.f);
    float4 a1 = a0, a2 = a0, a3 = a0;

    #pragma unroll 4
    for (int k = 0; k < 128; ++k) {
        float4 w = *(const float4*)(ws + k * 128 + col);
        float x0 = xs[(r0     ) * 128 + k];
        float x1 = xs[(r0 +  8) * 128 + k];
        float x2 = xs[(r0 + 16) * 128 + k];
        float x3 = xs[(r0 + 24) * 128 + k];
        a0.x += x0 * w.x; a0.y += x0 * w.y; a0.z += x0 * w.z; a0.w += x0 * w.w;
        a1.x += x1 * w.x; a1.y += x1 * w.y; a1.z += x1 * w.z; a1.w += x1 * w.w;
        a2.x += x2 * w.x; a2.y += x2 * w.y; a2.z += x2 * w.z; a2.w += x2 * w.w;
        a3.x += x3 * w.x; a3.y += x3 * w.y; a3.z += x3 * w.z; a3.w += x3 * w.w;
    }

    int gr;
    gr = base + r0;      if (gr < nrows) *(float4*)(Y + (long long)gr * 128 + col) = a0;
    gr = base + r0 + 8;  if (gr < nrows) *(float4*)(Y + (long long)gr * 128 + col) = a1;
    gr = base + r0 + 16; if (gr < nrows) *(float4*)(Y + (long long)gr * 128 + col) = a2;
    gr = base + r0 + 24; if (gr < nrows) *(float4*)(Y + (long long)gr * 128 + col) = a3;
}

// G[n x 40] = (H[n x 128] * scale[row]) @ Wp[128 x 40]
// LDS-staged Wp; each thread: 4 rows x 1 col.
__global__ __launch_bounds__(256) void gemm40(
        const float* __restrict__ H, const float* __restrict__ scale,
        const float* __restrict__ Wp, float* __restrict__ G, int n) {
    __shared__ float ws[128 * 40];   // 20 KB
    const int tid = threadIdx.x;
    for (int i = tid; i < 1280; i += 256) {
        *(float4*)(ws + i * 4) = *(const float4*)(Wp + i * 4);
    }
    __syncthreads();

    const int idx = blockIdx.x * 256 + tid;
    const int rg  = idx / 40;
    const int c   = idx - rg * 40;
    const int r0  = rg * 4;
    if (r0 >= n) return;

    const float* h = H + (long long)r0 * 128;

    if (r0 + 4 <= n) {
        float a0 = 0.f, a1 = 0.f, a2 = 0.f, a3 = 0.f;
        #pragma unroll 4
        for (int k = 0; k < 128; k += 4) {
            float4 x0 = *(const float4*)(h + k);
            float4 x1 = *(const float4*)(h + 128 + k);
            float4 x2 = *(const float4*)(h + 256 + k);
            float4 x3 = *(const float4*)(h + 384 + k);
            float w0 = ws[(k + 0) * 40 + c];
            float w1 = ws[(k + 1) * 40 + c];
            float w2 = ws[(k + 2) * 40 + c];
            float w3 = ws[(k + 3) * 40 + c];
            a0 += x0.x * w0 + x0.y * w1 + x0.z * w2 + x0.w * w3;
            a1 += x1.x * w0 + x1.y * w1 + x1.z * w2 + x1.w * w3;
            a2 += x2.x * w0 + x2.y * w1 + x2.z * w2 + x2.w * w3;
            a3 += x3.x * w0 + x3.y * w1 + x3.z * w2 + x3.w * w3;
        }
        G[(long long)(r0 + 0) * 40 + c] = a0 * scale[r0 + 0];
        G[(long long)(r0 + 1) * 40 + c] = a1 * scale[r0 + 1];
        G[(long long)(r0 + 2) * 40 + c] = a2 * scale[r0 + 2];
        G[(long long)(r0 + 3) * 40 + c] = a3 * scale[r0 + 3];
    } else {
        for (int r = r0; r < n; ++r) {
            const float* hr = H + (long long)r * 128;
            float a = 0.f;
            #pragma unroll 4
            for (int k = 0; k < 128; k += 4) {
                float4 x = *(const float4*)(hr + k);
                a += x.x * ws[(k + 0) * 40 + c] + x.y * ws[(k + 1) * 40 + c]
                   + x.z * ws[(k + 2) * 40 + c] + x.w * ws[(k + 3) * 40 + c];
            }
            G[(long long)r * 40 + c] = a * scale[r];
        }
    }
}

// 128-dim gather: out[node] = relu?((sum_{in} H[src]) * norm_in + b)
// 32 lanes per node (one float4/lane).
__global__ __launch_bounds__(256) void gather_kernel(
        const float* __restrict__ H, const int* __restrict__ row_ptr,
        const int* __restrict__ deg, const int* __restrict__ csr_src,
        const float* __restrict__ norm_in, const float* __restrict__ b,
        float* __restrict__ out, int n, int do_relu) {
    const int tid  = threadIdx.x;
    const int node = blockIdx.x * 8 + (tid >> 5);
    const int c    = (tid & 31) * 4;
    if (node >= n) return;

    const int start = row_ptr[node];
    const int cnt   = deg[node];
    float4 acc = make_float4(0.f, 0.f, 0.f, 0.f);

    int j = 0;
    for (; j + 4 <= cnt; j += 4) {
        int s0 = csr_src[start + j];
        int s1 = csr_src[start + j + 1];
        int s2 = csr_src[start + j + 2];
        int s3 = csr_src[start + j + 3];
        float4 v0 = *(const float4*)(H + (long long)s0 * 128 + c);
        float4 v1 = *(const float4*)(H + (long long)s1 * 128 + c);
        float4 v2 = *(const float4*)(H + (long long)s2 * 128 + c);
        float4 v3 = *(const float4*)(H + (long long)s3 * 128 + c);
        acc.x += (v0.x + v1.x) + (v2.x + v3.x);
        acc.y += (v0.y + v1.y) + (v2.y + v3.y);
        acc.z += (v0.z + v1.z) + (v2.z + v3.z);
        acc.w += (v0.w + v1.w) + (v2.w + v3.w);
    }
    for (; j < cnt; ++j) {
        int s0 = csr_src[start + j];
        float4 v0 = *(const float4*)(H + (long long)s0 * 128 + c);
        acc.x += v0.x; acc.y += v0.y; acc.z += v0.z; acc.w += v0.w;
    }

    float ni = norm_in[node];
    float4 bb = *(const float4*)(b + c);
    acc.x = acc.x * ni + bb.x;
    acc.y = acc.y * ni + bb.y;
    acc.z = acc.z * ni + bb.z;
    acc.w = acc.w * ni + bb.w;
    if (do_relu) {
        acc.x = fmaxf(acc.x, 0.f); acc.y = fmaxf(acc.y, 0.f);
        acc.z = fmaxf(acc.z, 0.f); acc.w = fmaxf(acc.w, 0.f);
    }
    *(float4*)(out + (long long)node * 128 + c) = acc;
}

// 40-dim gather (final): out[node] = (sum_{in} G[src]) * norm_in + b2p
// 10 threads per node (one float4 each); G row stride 40 floats (16B aligned).
__global__ __launch_bounds__(256) void gather40_kernel(
        const float* __restrict__ G, const int* __restrict__ row_ptr,
        const int* __restrict__ deg, const int* __restrict__ csr_src,
        const float* __restrict__ norm_in, const float* __restrict__ b2p,
        float* __restrict__ out, int n) {
    const int t = blockIdx.x * 256 + threadIdx.x;
    if (t >= n * 10) return;
    const int node = t / 10;
    const int c    = (t - node * 10) * 4;

    const int start = row_ptr[node];
    const int cnt   = deg[node];
    float4 acc = make_float4(0.f, 0.f, 0.f, 0.f);

    int j = 0;
    for (; j + 4 <= cnt; j += 4) {
        int s0 = csr_src[start + j];
        int s1 = csr_src[start + j + 1];
        int s2 = csr_src[start + j + 2];
        int s3 = csr_src[start + j + 3];
        float4 v0 = *(const float4*)(G + (long long)s0 * 40 + c);
        float4 v1 = *(const float4*)(G + (long long)s1 * 40 + c);
        float4 v2 = *(const float4*)(G + (long long)s2 * 40 + c);
        float4 v3 = *(const float4*)(G + (long long)s3 * 40 + c);
        acc.x += (v0.x + v1.x) + (v2.x + v3.x);
        acc.y += (v0.y + v1.y) + (v2.y + v3.y);
        acc.z += (v0.z + v1.z) + (v2.z + v3.z);
        acc.w += (v0.w + v1.w) + (v2.w + v3.w);
    }
    for (; j < cnt; ++j) {
        int s0 = csr_src[start + j];
        float4 v0 = *(const float4*)(G + (long long)s0 * 40 + c);
        acc.x += v0.x; acc.y += v0.y; acc.z += v0.z; acc.w += v0.w;
    }

    float ni = norm_in[node];
    float4 bb = *(const float4*)(b2p + c);
    acc.x = acc.x * ni + bb.x;
    acc.y = acc.y * ni + bb.y;
    acc.z = acc.z * ni + bb.z;
    acc.w = acc.w * ni + bb.w;
    *(float4*)(out + (long long)node * 40 + c) = acc;
}

extern "C" void kernel_launch(void* const* d_in, const int* in_sizes, int n_in,
                              void* d_out, int out_size, void* d_ws, size_t ws_size,
                              hipStream_t stream) {
    const float* x   = (const float*)d_in[0];
    const int*   ei  = (const int*)  d_in[1];
    const float* W1  = (const float*)d_in[2];
    const float* b1  = (const float*)d_in[3];
    const float* W2  = (const float*)d_in[4];
    const float* b2  = (const float*)d_in[5];
    const float* Wfc = (const float*)d_in[6];
    const float* bfc = (const float*)d_in[7];
    float* out = (float*)d_out;

    const int N = in_sizes[0] / 128;
    const int E = in_sizes[1] / 2;
    const int* src = ei;
    const int* dst = ei + E;
    const int n_scan_blocks = (N + SCAN_BLK - 1) / SCAN_BLK;

    char* p = (char*)d_ws;
    float* norm_out = (float*)p; p += (size_t)N * 4;
    float* norm_in  = (float*)p; p += (size_t)N * 4;
    float* bufA     = (float*)p; p += (size_t)N * 128 * 4;   // h1pre, then G (Nx40)
    float* bufB     = (float*)p; p += (size_t)N * 128 * 4;   // h1
    int*   deg_out  = (int*)p;   p += (size_t)N * 4;
    int*   deg_in   = (int*)p;   p += (size_t)N * 4;
    int*   row_ptr  = (int*)p;   p += (size_t)N * 4;
    int*   rank     = (int*)p;   p += (size_t)E * 4;
    int*   csr_src  = (int*)p;   p += (size_t)E * 4;
    int*   aux      = (int*)p;   p += (size_t)((n_scan_blocks + 3) & ~3) * 4;
    float* W2p      = (float*)p; p += (size_t)128 * 40 * 4;
    float* b2p      = (float*)p; p += (size_t)64 * 4;

    const int T = 256;

    hipMemsetAsync(deg_out, 0, (size_t)N * 8, stream);
    deg_kernel<<<(E + T - 1) / T, T, 0, stream>>>(src, dst, deg_out, deg_in, rank, E);
    norm_kernel<<<(N + T - 1) / T, T, 0, stream>>>(deg_out, deg_in, norm_out, norm_in, N);

    // fold layer2+FC weights (independent of graph work)
    fold_w2_kernel<<<(129 * 40 + T - 1) / T, T, 0, stream>>>(W2, Wfc, b2, bfc, W2p, b2p);

    // CSR build (atomic-free fill)
    scan_block_kernel<<<n_scan_blocks, 256, 0, stream>>>(deg_in, row_ptr, aux, N);
    scan_aux_kernel<<<1, 1024, 0, stream>>>(aux, n_scan_blocks);
    add_offsets_kernel<<<(N + T - 1) / T, T, 0, stream>>>(row_ptr, aux, N);
    fill_csr_kernel<<<(E + T - 1) / T, T, 0, stream>>>(src, dst, rank, row_ptr, csr_src, E);

    const int gemm_grid   = (N + 31) / 32;
    const int gather_grid = (N + 7) / 8;

    // layer 0: h1 = relu(gather(Xn @ W1) * ni + b1)
    gemm128<<<gemm_grid, T, 0, stream>>>(x, norm_out, W1, bufA, N);
    gather_kernel<<<gather_grid, T, 0, stream>>>(bufA, row_ptr, deg_in, csr_src,
                                                 norm_in, b1, bufB, N, 1);
    // layer 1 + FC fused: out = gather((h1*no) @ W2p) * ni + b2p
    const int g40_grid = ((N + 3) / 4 * 40 + T - 1) / T;
    gemm40<<<g40_grid, T, 0, stream>>>(bufB, norm_out, W2p, bufA, N);
    gather40_kernel<<<((size_t)N * 10 + T - 1) / T, T, 0, stream>>>(
        bufA, row_ptr, deg_in, csr_src, norm_in, b2p, out, N);
}

// Round 5
// 502.856 us; speedup vs baseline: 11.8199x; 1.1629x over previous
//
#include <hip/hip_runtime.h>

// ---------------------------------------------------------------------------
// GCN: 2x GraphConv (norm='both') + FC.  All fp32.
// R2: CSR gather instead of atomic scatter (5943 -> 840 us).
// R3: LDS-staged fc, gather unroll-4 (840 -> 782 us).
// R4: atomic-free CSR fill (rank trick); fold layer2+FC (782 -> 585 us).
// R5: ZERO per-edge global atomics. deg_kernel (160 us, 106 MB atomic
//     write-through) replaced by 2-level counting sort keyed on node>>9:
//     LDS-histogram coarse count -> scan -> LDS-cursor partition ->
//     per-bucket fine kernels that emit deg/norm/row_ptr/csr_src with
//     LDS atomics + plain stores only.
// ---------------------------------------------------------------------------

#define SCAN_BLK 1024   // elements per scan block
#define CHUNK    4096   // edges per coarse block
#define NB       256    // coarse buckets (node>>9; 100000>>9 = 195 max)

// ---------------- generic scan (used for the 200K coarse-count array) -------
__global__ __launch_bounds__(256) void scan_block_kernel(
        const int* __restrict__ in, int* __restrict__ out, int* __restrict__ aux, int n) {
    __shared__ int sdata[256];
    const int tid = threadIdx.x;
    const int base = blockIdx.x * SCAN_BLK + tid * 4;
    int v0 = (base + 0 < n) ? in[base + 0] : 0;
    int v1 = (base + 1 < n) ? in[base + 1] : 0;
    int v2 = (base + 2 < n) ? in[base + 2] : 0;
    int v3 = (base + 3 < n) ? in[base + 3] : 0;
    int tot = v0 + v1 + v2 + v3;
    sdata[tid] = tot;
    __syncthreads();
    for (int off = 1; off < 256; off <<= 1) {
        int t = (tid >= off) ? sdata[tid - off] : 0;
        __syncthreads();
        sdata[tid] += t;
        __syncthreads();
    }
    int excl = sdata[tid] - tot;
    if (base + 0 < n) out[base + 0] = excl;
    if (base + 1 < n) out[base + 1] = excl + v0;
    if (base + 2 < n) out[base + 2] = excl + v0 + v1;
    if (base + 3 < n) out[base + 3] = excl + v0 + v1 + v2;
    if (tid == 255) aux[blockIdx.x] = sdata[255];
}

__global__ __launch_bounds__(1024) void scan_aux_kernel(int* __restrict__ aux, int nb) {
    __shared__ int sdata[1024];
    const int tid = threadIdx.x;
    int v = (tid < nb) ? aux[tid] : 0;
    sdata[tid] = v;
    __syncthreads();
    for (int off = 1; off < 1024; off <<= 1) {
        int t = (tid >= off) ? sdata[tid - off] : 0;
        __syncthreads();
        sdata[tid] += t;
        __syncthreads();
    }
    if (tid < nb) aux[tid] = sdata[tid] - v;   // exclusive
}

__global__ void add_offsets_kernel(int* __restrict__ arr, const int* __restrict__ aux, int n) {
    int i = blockIdx.x * blockDim.x + threadIdx.x;
    if (i < n) arr[i] += aux[i / SCAN_BLK];
}

// ------------- stage 1: coarse count (LDS histograms, plain stores) ---------
// counts layout: [bin*B1 + blk] for dst;  [(NB+bin)*B1 + blk] for src.
__global__ __launch_bounds__(256) void count_coarse_kernel(
        const int* __restrict__ src, const int* __restrict__ dst,
        int* __restrict__ counts, int E, int B1) {
    __shared__ int hd[NB], hs[NB];
    const int tid = threadIdx.x;
    hd[tid] = 0; hs[tid] = 0;
    __syncthreads();
    const int base = blockIdx.x * CHUNK;
    for (int i = tid; i < CHUNK; i += 256) {
        int e = base + i;
        if (e < E) {
            atomicAdd(&hd[((unsigned)dst[e]) >> 9], 1);
            atomicAdd(&hs[((unsigned)src[e]) >> 9], 1);
        }
    }
    __syncthreads();
    counts[tid * B1 + blockIdx.x]        = hd[tid];
    counts[(NB + tid) * B1 + blockIdx.x] = hs[tid];
}

// ------------- stage 2: partition edges by coarse bucket (LDS cursors) ------
__global__ __launch_bounds__(256) void scatter_coarse_kernel(
        const int* __restrict__ src, const int* __restrict__ dst,
        const int* __restrict__ coff,
        int* __restrict__ pdst, int* __restrict__ psrc, int* __restrict__ es_src,
        int E, int B1) {
    __shared__ int cd[NB], cs[NB];
    const int tid = threadIdx.x;
    cd[tid] = coff[tid * B1 + blockIdx.x];
    cs[tid] = coff[(NB + tid) * B1 + blockIdx.x] - E;   // src section offset by E
    __syncthreads();
    const int base = blockIdx.x * CHUNK;
    for (int i = tid; i < CHUNK; i += 256) {
        int e = base + i;
        if (e < E) {
            int d = dst[e], s = src[e];
            int pd = atomicAdd(&cd[((unsigned)d) >> 9], 1);
            pdst[pd] = d;
            psrc[pd] = s;
            int ps = atomicAdd(&cs[((unsigned)s) >> 9], 1);
            es_src[ps] = s;
        }
    }
}

// ------------- stage 3a: per-bucket fine pass for dst ----------------------
// Bucket b owns nodes [b*512, b*512+512). Its edges are contiguous in the
// partition: [coff[b*B1], coff[(b+1)*B1]) (index NB*B1 = start of src scan = E).
// Emits deg_in, norm_in, row_ptr (local scan + bucket base) and csr_src.
__global__ __launch_bounds__(256) void fine_dst_kernel(
        const int* __restrict__ pdst, const int* __restrict__ psrc,
        const int* __restrict__ coff,
        int* __restrict__ deg_in, float* __restrict__ norm_in,
        int* __restrict__ row_ptr, int* __restrict__ csr_src,
        int N_, int B1) {
    __shared__ int h[512];
    __shared__ int psum[256];
    const int tid = threadIdx.x;
    const int b = blockIdx.x;
    const int start = coff[b * B1];
    const int end   = coff[(b + 1) * B1];
    const int node0 = b * 512;

    h[tid] = 0; h[tid + 256] = 0;
    __syncthreads();
    for (int i = start + tid; i < end; i += 256)
        atomicAdd(&h[pdst[i] - node0], 1);
    __syncthreads();

    // exclusive scan of 512 bins (2 per thread)
    int a0 = h[2 * tid], a1 = h[2 * tid + 1];
    int pair = a0 + a1;
    psum[tid] = pair;
    __syncthreads();
    for (int off = 1; off < 256; off <<= 1) {
        int t = (tid >= off) ? psum[tid - off] : 0;
        __syncthreads();
        psum[tid] += t;
        __syncthreads();
    }
    int base0 = psum[tid] - pair + start;   // global CSR pos of bin 2*tid

    int n0 = node0 + 2 * tid, n1 = n0 + 1;
    if (n0 < N_) {
        deg_in[n0]  = a0;
        row_ptr[n0] = base0;
        norm_in[n0] = rsqrtf((float)(a0 < 1 ? 1 : a0));
    }
    if (n1 < N_) {
        deg_in[n1]  = a1;
        row_ptr[n1] = base0 + a0;
        norm_in[n1] = rsqrtf((float)(a1 < 1 ? 1 : a1));
    }
    h[2 * tid]     = base0;        // cursors
    h[2 * tid + 1] = base0 + a0;
    __syncthreads();

    for (int i = start + tid; i < end; i += 256) {
        int pos = atomicAdd(&h[pdst[i] - node0], 1);
        csr_src[pos] = psrc[i];
    }
}

// ------------- stage 3b: per-bucket fine pass for src (norm_out only) -------
__global__ __launch_bounds__(256) void fine_src_kernel(
        const int* __restrict__ es_src, const int* __restrict__ coff,
        float* __restrict__ norm_out, int N_, int E, int B1) {
    __shared__ int h[512];
    const int tid = threadIdx.x;
    const int b = blockIdx.x;
    const int start = coff[(NB + b) * B1] - E;
    const int end   = (b == NB - 1) ? E : coff[(NB + b + 1) * B1] - E;
    const int node0 = b * 512;

    h[tid] = 0; h[tid + 256] = 0;
    __syncthreads();
    for (int i = start + tid; i < end; i += 256)
        atomicAdd(&h[es_src[i] - node0], 1);
    __syncthreads();

    int n0 = node0 + tid, n1 = n0 + 256;
    if (n0 < N_) { int d = h[tid];       norm_out[n0] = rsqrtf((float)(d < 1 ? 1 : d)); }
    if (n1 < N_) { int d = h[tid + 256]; norm_out[n1] = rsqrtf((float)(d < 1 ? 1 : d)); }
}

// W2p[128x40] = W2[128x128] @ Wfc[128x40];  b2p[40] = b2 @ Wfc + bfc
__global__ void fold_w2_kernel(const float* __restrict__ W2, const float* __restrict__ Wfc,
                               const float* __restrict__ b2, const float* __restrict__ bfc,
                               float* __restrict__ W2p, float* __restrict__ b2p) {
    int idx = blockIdx.x * blockDim.x + threadIdx.x;
    if (idx < 128 * 40) {
        int k = idx / 40, c = idx - (idx / 40) * 40;
        const float* w2row = W2 + k * 128;
        float a = 0.f;
        #pragma unroll 8
        for (int j = 0; j < 128; ++j) a += w2row[j] * Wfc[j * 40 + c];
        W2p[idx] = a;
    } else if (idx < 129 * 40) {
        int c = idx - 128 * 40;
        float a = bfc[c];
        #pragma unroll 8
        for (int j = 0; j < 128; ++j) a += b2[j] * Wfc[j * 40 + c];
        b2p[c] = a;
    }
}

// Y[nrows x 128] = (X[nrows x 128] * scale[row]) @ W[128 x 128]
__global__ __launch_bounds__(256) void gemm128(
        const float* __restrict__ X, const float* __restrict__ scale,
        const float* __restrict__ W, float* __restrict__ Y, int nrows) {
    __shared__ float xs[32 * 128];   // 16 KB
    __shared__ float ws[128 * 128];  // 64 KB
    const int tid = threadIdx.x;
    const int base = blockIdx.x * 32;

    for (int i = tid; i < 4096; i += 256) {
        *(float4*)(ws + i * 4) = *(const float4*)(W + i * 4);
    }
    for (int i = tid; i < 1024; i += 256) {
        int r  = i >> 5;
        int k4 = (i & 31) * 4;
        int gr = base + r;
        float4 v = make_float4(0.f, 0.f, 0.f, 0.f);
        if (gr < nrows) {
            v = *(const float4*)(X + (long long)gr * 128 + k4);
            float sc = scale[gr];
            v.x *= sc; v.y *= sc; v.z *= sc; v.w *= sc;
        }
        *(float4*)(xs + r * 128 + k4) = v;
    }
    __syncthreads();

    const int r0  = tid >> 5;
    const int col = (tid & 31) * 4;
    float4 a0 = make_float4(0.f,0.f,0.f,0.f);
    float4 a1 = a0, a2 = a0, a3 = a0;

    #pragma unroll 4
    for (int k = 0; k < 128; ++k) {
        float4 w = *(const float4*)(ws + k * 128 + col);
        float x0 = xs[(r0     ) * 128 + k];
        float x1 = xs[(r0 +  8) * 128 + k];
        float x2 = xs[(r0 + 16) * 128 + k];
        float x3 = xs[(r0 + 24) * 128 + k];
        a0.x += x0 * w.x; a0.y += x0 * w.y; a0.z += x0 * w.z; a0.w += x0 * w.w;
        a1.x += x1 * w.x; a1.y += x1 * w.y; a1.z += x1 * w.z; a1.w += x1 * w.w;
        a2.x += x2 * w.x; a2.y += x2 * w.y; a2.z += x2 * w.z; a2.w += x2 * w.w;
        a3.x += x3 * w.x; a3.y += x3 * w.y; a3.z += x3 * w.z; a3.w += x3 * w.w;
    }

    int gr;
    gr = base + r0;      if (gr < nrows) *(float4*)(Y + (long long)gr * 128 + col) = a0;
    gr = base + r0 + 8;  if (gr < nrows) *(float4*)(Y + (long long)gr * 128 + col) = a1;
    gr = base + r0 + 16; if (gr < nrows) *(float4*)(Y + (long long)gr * 128 + col) = a2;
    gr = base + r0 + 24; if (gr < nrows) *(float4*)(Y + (long long)gr * 128 + col) = a3;
}

// G[n x 40] = (H[n x 128] * scale[row]) @ Wp[128 x 40]
__global__ __launch_bounds__(256) void gemm40(
        const float* __restrict__ H, const float* __restrict__ scale,
        const float* __restrict__ Wp, float* __restrict__ G, int n) {
    __shared__ float ws[128 * 40];   // 20 KB
    const int tid = threadIdx.x;
    for (int i = tid; i < 1280; i += 256) {
        *(float4*)(ws + i * 4) = *(const float4*)(Wp + i * 4);
    }
    __syncthreads();

    const int idx = blockIdx.x * 256 + tid;
    const int rg  = idx / 40;
    const int c   = idx - rg * 40;
    const int r0  = rg * 4;
    if (r0 >= n) return;

    const float* h = H + (long long)r0 * 128;

    if (r0 + 4 <= n) {
        float a0 = 0.f, a1 = 0.f, a2 = 0.f, a3 = 0.f;
        #pragma unroll 4
        for (int k = 0; k < 128; k += 4) {
            float4 x0 = *(const float4*)(h + k);
            float4 x1 = *(const float4*)(h + 128 + k);
            float4 x2 = *(const float4*)(h + 256 + k);
            float4 x3 = *(const float4*)(h + 384 + k);
            float w0 = ws[(k + 0) * 40 + c];
            float w1 = ws[(k + 1) * 40 + c];
            float w2 = ws[(k + 2) * 40 + c];
            float w3 = ws[(k + 3) * 40 + c];
            a0 += x0.x * w0 + x0.y * w1 + x0.z * w2 + x0.w * w3;
            a1 += x1.x * w0 + x1.y * w1 + x1.z * w2 + x1.w * w3;
            a2 += x2.x * w0 + x2.y * w1 + x2.z * w2 + x2.w * w3;
            a3 += x3.x * w0 + x3.y * w1 + x3.z * w2 + x3.w * w3;
        }
        G[(long long)(r0 + 0) * 40 + c] = a0 * scale[r0 + 0];
        G[(long long)(r0 + 1) * 40 + c] = a1 * scale[r0 + 1];
        G[(long long)(r0 + 2) * 40 + c] = a2 * scale[r0 + 2];
        G[(long long)(r0 + 3) * 40 + c] = a3 * scale[r0 + 3];
    } else {
        for (int r = r0; r < n; ++r) {
            const float* hr = H + (long long)r * 128;
            float a = 0.f;
            #pragma unroll 4
            for (int k = 0; k < 128; k += 4) {
                float4 x = *(const float4*)(hr + k);
                a += x.x * ws[(k + 0) * 40 + c] + x.y * ws[(k + 1) * 40 + c]
                   + x.z * ws[(k + 2) * 40 + c] + x.w * ws[(k + 3) * 40 + c];
            }
            G[(long long)r * 40 + c] = a * scale[r];
        }
    }
}

// 128-dim gather: out[node] = relu?((sum_{in} H[src]) * norm_in + b)
__global__ __launch_bounds__(256) void gather_kernel(
        const float* __restrict__ H, const int* __restrict__ row_ptr,
        const int* __restrict__ deg, const int* __restrict__ csr_src,
        const float* __restrict__ norm_in, const float* __restrict__ b,
        float* __restrict__ out, int n, int do_relu) {
    const int tid  = threadIdx.x;
    const int node = blockIdx.x * 8 + (tid >> 5);
    const int c    = (tid & 31) * 4;
    if (node >= n) return;

    const int start = row_ptr[node];
    const int cnt   = deg[node];
    float4 acc = make_float4(0.f, 0.f, 0.f, 0.f);

    int j = 0;
    for (; j + 4 <= cnt; j += 4) {
        int s0 = csr_src[start + j];
        int s1 = csr_src[start + j + 1];
        int s2 = csr_src[start + j + 2];
        int s3 = csr_src[start + j + 3];
        float4 v0 = *(const float4*)(H + (long long)s0 * 128 + c);
        float4 v1 = *(const float4*)(H + (long long)s1 * 128 + c);
        float4 v2 = *(const float4*)(H + (long long)s2 * 128 + c);
        float4 v3 = *(const float4*)(H + (long long)s3 * 128 + c);
        acc.x += (v0.x + v1.x) + (v2.x + v3.x);
        acc.y += (v0.y + v1.y) + (v2.y + v3.y);
        acc.z += (v0.z + v1.z) + (v2.z + v3.z);
        acc.w += (v0.w + v1.w) + (v2.w + v3.w);
    }
    for (; j < cnt; ++j) {
        int s0 = csr_src[start + j];
        float4 v0 = *(const float4*)(H + (long long)s0 * 128 + c);
        acc.x += v0.x; acc.y += v0.y; acc.z += v0.z; acc.w += v0.w;
    }

    float ni = norm_in[node];
    float4 bb = *(const float4*)(b + c);
    acc.x = acc.x * ni + bb.x;
    acc.y = acc.y * ni + bb.y;
    acc.z = acc.z * ni + bb.z;
    acc.w = acc.w * ni + bb.w;
    if (do_relu) {
        acc.x = fmaxf(acc.x, 0.f); acc.y = fmaxf(acc.y, 0.f);
        acc.z = fmaxf(acc.z, 0.f); acc.w = fmaxf(acc.w, 0.f);
    }
    *(float4*)(out + (long long)node * 128 + c) = acc;
}

// 40-dim gather (final): out[node] = (sum_{in} G[src]) * norm_in + b2p
__global__ __launch_bounds__(256) void gather40_kernel(
        const float* __restrict__ G, const int* __restrict__ row_ptr,
        const int* __restrict__ deg, const int* __restrict__ csr_src,
        const float* __restrict__ norm_in, const float* __restrict__ b2p,
        float* __restrict__ out, int n) {
    const int t = blockIdx.x * 256 + threadIdx.x;
    if (t >= n * 10) return;
    const int node = t / 10;
    const int c    = (t - node * 10) * 4;

    const int start = row_ptr[node];
    const int cnt   = deg[node];
    float4 acc = make_float4(0.f, 0.f, 0.f, 0.f);

    int j = 0;
    for (; j + 4 <= cnt; j += 4) {
        int s0 = csr_src[start + j];
        int s1 = csr_src[start + j + 1];
        int s2 = csr_src[start + j + 2];
        int s3 = csr_src[start + j + 3];
        float4 v0 = *(const float4*)(G + (long long)s0 * 40 + c);
        float4 v1 = *(const float4*)(G + (long long)s1 * 40 + c);
        float4 v2 = *(const float4*)(G + (long long)s2 * 40 + c);
        float4 v3 = *(const float4*)(G + (long long)s3 * 40 + c);
        acc.x += (v0.x + v1.x) + (v2.x + v3.x);
        acc.y += (v0.y + v1.y) + (v2.y + v3.y);
        acc.z += (v0.z + v1.z) + (v2.z + v3.z);
        acc.w += (v0.w + v1.w) + (v2.w + v3.w);
    }
    for (; j < cnt; ++j) {
        int s0 = csr_src[start + j];
        float4 v0 = *(const float4*)(G + (long long)s0 * 40 + c);
        acc.x += v0.x; acc.y += v0.y; acc.z += v0.z; acc.w += v0.w;
    }

    float ni = norm_in[node];
    float4 bb = *(const float4*)(b2p + c);
    acc.x = acc.x * ni + bb.x;
    acc.y = acc.y * ni + bb.y;
    acc.z = acc.z * ni + bb.z;
    acc.w = acc.w * ni + bb.w;
    *(float4*)(out + (long long)node * 40 + c) = acc;
}

extern "C" void kernel_launch(void* const* d_in, const int* in_sizes, int n_in,
                              void* d_out, int out_size, void* d_ws, size_t ws_size,
                              hipStream_t stream) {
    const float* x   = (const float*)d_in[0];
    const int*   ei  = (const int*)  d_in[1];
    const float* W1  = (const float*)d_in[2];
    const float* b1  = (const float*)d_in[3];
    const float* W2  = (const float*)d_in[4];
    const float* b2  = (const float*)d_in[5];
    const float* Wfc = (const float*)d_in[6];
    const float* bfc = (const float*)d_in[7];
    float* out = (float*)d_out;

    const int N = in_sizes[0] / 128;
    const int E = in_sizes[1] / 2;
    const int* src = ei;
    const int* dst = ei + E;

    const int B1 = (E + CHUNK - 1) / CHUNK;            // coarse blocks (391)
    const int n_counts = 2 * NB * B1;                   // 200192
    const int n_scan_blocks = (n_counts + SCAN_BLK - 1) / SCAN_BLK;

    char* p = (char*)d_ws;
    float* norm_out = (float*)p; p += (size_t)N * 4;
    float* norm_in  = (float*)p; p += (size_t)N * 4;
    float* bufA     = (float*)p; p += (size_t)N * 128 * 4;   // h1pre, then G (Nx40)
    float* bufB     = (float*)p; p += (size_t)N * 128 * 4;   // h1 (aliased early: partitions)
    int*   deg_in   = (int*)p;   p += (size_t)N * 4;
    int*   row_ptr  = (int*)p;   p += (size_t)N * 4;
    int*   csr_src  = (int*)p;   p += (size_t)E * 4;
    int*   counts   = (int*)p;   p += (size_t)n_counts * 4;
    int*   coff     = (int*)p;   p += (size_t)n_counts * 4;
    int*   aux      = (int*)p;   p += (size_t)((n_scan_blocks + 3) & ~3) * 4;
    float* W2p      = (float*)p; p += (size_t)128 * 40 * 4;
    float* b2p      = (float*)p; p += (size_t)64 * 4;

    // partition buffers alias bufB (consumed by fine kernels before gather
    // writes h1 into bufB; stream order guarantees safety). 3*E*4 = 19.2 MB < 51.2 MB.
    int* pdst   = (int*)bufB;
    int* psrc   = pdst + E;
    int* es_src = psrc + E;

    const int T = 256;

    // ---- CSR build + norms: zero per-edge global atomics ----
    count_coarse_kernel<<<B1, T, 0, stream>>>(src, dst, counts, E, B1);
    scan_block_kernel<<<n_scan_blocks, T, 0, stream>>>(counts, coff, aux, n_counts);
    scan_aux_kernel<<<1, 1024, 0, stream>>>(aux, n_scan_blocks);
    add_offsets_kernel<<<(n_counts + T - 1) / T, T, 0, stream>>>(coff, aux, n_counts);
    scatter_coarse_kernel<<<B1, T, 0, stream>>>(src, dst, coff, pdst, psrc, es_src, E, B1);
    fine_dst_kernel<<<NB, T, 0, stream>>>(pdst, psrc, coff, deg_in, norm_in,
                                          row_ptr, csr_src, N, B1);
    fine_src_kernel<<<NB, T, 0, stream>>>(es_src, coff, norm_out, N, E, B1);

    // fold layer2+FC weights
    fold_w2_kernel<<<(129 * 40 + T - 1) / T, T, 0, stream>>>(W2, Wfc, b2, bfc, W2p, b2p);

    const int gemm_grid   = (N + 31) / 32;
    const int gather_grid = (N + 7) / 8;

    // layer 0: h1 = relu(gather(Xn @ W1) * ni + b1)
    gemm128<<<gemm_grid, T, 0, stream>>>(x, norm_out, W1, bufA, N);
    gather_kernel<<<gather_grid, T, 0, stream>>>(bufA, row_ptr, deg_in, csr_src,
                                                 norm_in, b1, bufB, N, 1);
    // layer 1 + FC fused: out = gather((h1*no) @ W2p) * ni + b2p
    const int g40_grid = ((N + 3) / 4 * 40 + T - 1) / T;
    gemm40<<<g40_grid, T, 0, stream>>>(bufB, norm_out, W2p, bufA, N);
    gather40_kernel<<<((size_t)N * 10 + T - 1) / T, T, 0, stream>>>(
        bufA, row_ptr, deg_in, csr_src, norm_in, b2p, out, N);
}

// Round 6
// 422.942 us; speedup vs baseline: 14.0533x; 1.1889x over previous
//
#include <hip/hip_runtime.h>
#include <hip/hip_fp16.h>

// ---------------------------------------------------------------------------
// GCN: 2x GraphConv (norm='both') + FC.  fp32 math, fp16 gather intermediates.
// R2: CSR gather instead of atomic scatter (5943 -> 840 us).
// R3: LDS-staged fc, gather unroll-4 (840 -> 782 us).
// R4: atomic-free CSR fill (rank trick); fold layer2+FC (782 -> 585 us).
// R5: zero per-edge global atomics: 2-level counting sort (585 -> 503 us).
// R6: gather is L2-miss-BW-bound (378 MB FETCH vs 51 MB working set):
//     store gathered matrices (h1pre, G) as fp16 -> bytes/row halved;
//     fp32 accumulation; gather unrolled 8-deep to keep bytes-in-flight.
// ---------------------------------------------------------------------------

#define SCAN_BLK 1024   // elements per scan block
#define CHUNK    4096   // edges per coarse block
#define NB       256    // coarse buckets (node>>9; 100000>>9 = 195 max)

struct __align__(8) half4 { __half x, y, z, w; };

__device__ __forceinline__ void acc_half4(float4& acc, const half4 v) {
    acc.x += __half2float(v.x);
    acc.y += __half2float(v.y);
    acc.z += __half2float(v.z);
    acc.w += __half2float(v.w);
}

// ---------------- generic scan (used for the 200K coarse-count array) -------
__global__ __launch_bounds__(256) void scan_block_kernel(
        const int* __restrict__ in, int* __restrict__ out, int* __restrict__ aux, int n) {
    __shared__ int sdata[256];
    const int tid = threadIdx.x;
    const int base = blockIdx.x * SCAN_BLK + tid * 4;
    int v0 = (base + 0 < n) ? in[base + 0] : 0;
    int v1 = (base + 1 < n) ? in[base + 1] : 0;
    int v2 = (base + 2 < n) ? in[base + 2] : 0;
    int v3 = (base + 3 < n) ? in[base + 3] : 0;
    int tot = v0 + v1 + v2 + v3;
    sdata[tid] = tot;
    __syncthreads();
    for (int off = 1; off < 256; off <<= 1) {
        int t = (tid >= off) ? sdata[tid - off] : 0;
        __syncthreads();
        sdata[tid] += t;
        __syncthreads();
    }
    int excl = sdata[tid] - tot;
    if (base + 0 < n) out[base + 0] = excl;
    if (base + 1 < n) out[base + 1] = excl + v0;
    if (base + 2 < n) out[base + 2] = excl + v0 + v1;
    if (base + 3 < n) out[base + 3] = excl + v0 + v1 + v2;
    if (tid == 255) aux[blockIdx.x] = sdata[255];
}

__global__ __launch_bounds__(1024) void scan_aux_kernel(int* __restrict__ aux, int nb) {
    __shared__ int sdata[1024];
    const int tid = threadIdx.x;
    int v = (tid < nb) ? aux[tid] : 0;
    sdata[tid] = v;
    __syncthreads();
    for (int off = 1; off < 1024; off <<= 1) {
        int t = (tid >= off) ? sdata[tid - off] : 0;
        __syncthreads();
        sdata[tid] += t;
        __syncthreads();
    }
    if (tid < nb) aux[tid] = sdata[tid] - v;   // exclusive
}

__global__ void add_offsets_kernel(int* __restrict__ arr, const int* __restrict__ aux, int n) {
    int i = blockIdx.x * blockDim.x + threadIdx.x;
    if (i < n) arr[i] += aux[i / SCAN_BLK];
}

// ------------- stage 1: coarse count (LDS histograms, plain stores) ---------
__global__ __launch_bounds__(256) void count_coarse_kernel(
        const int* __restrict__ src, const int* __restrict__ dst,
        int* __restrict__ counts, int E, int B1) {
    __shared__ int hd[NB], hs[NB];
    const int tid = threadIdx.x;
    hd[tid] = 0; hs[tid] = 0;
    __syncthreads();
    const int base = blockIdx.x * CHUNK;
    for (int i = tid; i < CHUNK; i += 256) {
        int e = base + i;
        if (e < E) {
            atomicAdd(&hd[((unsigned)dst[e]) >> 9], 1);
            atomicAdd(&hs[((unsigned)src[e]) >> 9], 1);
        }
    }
    __syncthreads();
    counts[tid * B1 + blockIdx.x]        = hd[tid];
    counts[(NB + tid) * B1 + blockIdx.x] = hs[tid];
}

// ------------- stage 2: partition edges by coarse bucket (LDS cursors) ------
__global__ __launch_bounds__(256) void scatter_coarse_kernel(
        const int* __restrict__ src, const int* __restrict__ dst,
        const int* __restrict__ coff,
        int* __restrict__ pdst, int* __restrict__ psrc, int* __restrict__ es_src,
        int E, int B1) {
    __shared__ int cd[NB], cs[NB];
    const int tid = threadIdx.x;
    cd[tid] = coff[tid * B1 + blockIdx.x];
    cs[tid] = coff[(NB + tid) * B1 + blockIdx.x] - E;   // src section offset by E
    __syncthreads();
    const int base = blockIdx.x * CHUNK;
    for (int i = tid; i < CHUNK; i += 256) {
        int e = base + i;
        if (e < E) {
            int d = dst[e], s = src[e];
            int pd = atomicAdd(&cd[((unsigned)d) >> 9], 1);
            pdst[pd] = d;
            psrc[pd] = s;
            int ps = atomicAdd(&cs[((unsigned)s) >> 9], 1);
            es_src[ps] = s;
        }
    }
}

// ------------- stage 3a: per-bucket fine pass for dst ----------------------
__global__ __launch_bounds__(256) void fine_dst_kernel(
        const int* __restrict__ pdst, const int* __restrict__ psrc,
        const int* __restrict__ coff,
        int* __restrict__ deg_in, float* __restrict__ norm_in,
        int* __restrict__ row_ptr, int* __restrict__ csr_src,
        int N_, int B1) {
    __shared__ int h[512];
    __shared__ int psum[256];
    const int tid = threadIdx.x;
    const int b = blockIdx.x;
    const int start = coff[b * B1];
    const int end   = coff[(b + 1) * B1];
    const int node0 = b * 512;

    h[tid] = 0; h[tid + 256] = 0;
    __syncthreads();
    for (int i = start + tid; i < end; i += 256)
        atomicAdd(&h[pdst[i] - node0], 1);
    __syncthreads();

    int a0 = h[2 * tid], a1 = h[2 * tid + 1];
    int pair = a0 + a1;
    psum[tid] = pair;
    __syncthreads();
    for (int off = 1; off < 256; off <<= 1) {
        int t = (tid >= off) ? psum[tid - off] : 0;
        __syncthreads();
        psum[tid] += t;
        __syncthreads();
    }
    int base0 = psum[tid] - pair + start;

    int n0 = node0 + 2 * tid, n1 = n0 + 1;
    if (n0 < N_) {
        deg_in[n0]  = a0;
        row_ptr[n0] = base0;
        norm_in[n0] = rsqrtf((float)(a0 < 1 ? 1 : a0));
    }
    if (n1 < N_) {
        deg_in[n1]  = a1;
        row_ptr[n1] = base0 + a0;
        norm_in[n1] = rsqrtf((float)(a1 < 1 ? 1 : a1));
    }
    h[2 * tid]     = base0;
    h[2 * tid + 1] = base0 + a0;
    __syncthreads();

    for (int i = start + tid; i < end; i += 256) {
        int pos = atomicAdd(&h[pdst[i] - node0], 1);
        csr_src[pos] = psrc[i];
    }
}

// ------------- stage 3b: per-bucket fine pass for src (norm_out only) -------
__global__ __launch_bounds__(256) void fine_src_kernel(
        const int* __restrict__ es_src, const int* __restrict__ coff,
        float* __restrict__ norm_out, int N_, int E, int B1) {
    __shared__ int h[512];
    const int tid = threadIdx.x;
    const int b = blockIdx.x;
    const int start = coff[(NB + b) * B1] - E;
    const int end   = (b == NB - 1) ? E : coff[(NB + b + 1) * B1] - E;
    const int node0 = b * 512;

    h[tid] = 0; h[tid + 256] = 0;
    __syncthreads();
    for (int i = start + tid; i < end; i += 256)
        atomicAdd(&h[es_src[i] - node0], 1);
    __syncthreads();

    int n0 = node0 + tid, n1 = n0 + 256;
    if (n0 < N_) { int d = h[tid];       norm_out[n0] = rsqrtf((float)(d < 1 ? 1 : d)); }
    if (n1 < N_) { int d = h[tid + 256]; norm_out[n1] = rsqrtf((float)(d < 1 ? 1 : d)); }
}

// W2p[128x40] = W2[128x128] @ Wfc[128x40];  b2p[40] = b2 @ Wfc + bfc
__global__ void fold_w2_kernel(const float* __restrict__ W2, const float* __restrict__ Wfc,
                               const float* __restrict__ b2, const float* __restrict__ bfc,
                               float* __restrict__ W2p, float* __restrict__ b2p) {
    int idx = blockIdx.x * blockDim.x + threadIdx.x;
    if (idx < 128 * 40) {
        int k = idx / 40, c = idx - (idx / 40) * 40;
        const float* w2row = W2 + k * 128;
        float a = 0.f;
        #pragma unroll 8
        for (int j = 0; j < 128; ++j) a += w2row[j] * Wfc[j * 40 + c];
        W2p[idx] = a;
    } else if (idx < 129 * 40) {
        int c = idx - 128 * 40;
        float a = bfc[c];
        #pragma unroll 8
        for (int j = 0; j < 128; ++j) a += b2[j] * Wfc[j * 40 + c];
        b2p[c] = a;
    }
}

// Y[nrows x 128] (fp16) = (X[nrows x 128] * scale[row]) @ W[128 x 128]
__global__ __launch_bounds__(256) void gemm128(
        const float* __restrict__ X, const float* __restrict__ scale,
        const float* __restrict__ W, __half* __restrict__ Y, int nrows) {
    __shared__ float xs[32 * 128];   // 16 KB
    __shared__ float ws[128 * 128];  // 64 KB
    const int tid = threadIdx.x;
    const int base = blockIdx.x * 32;

    for (int i = tid; i < 4096; i += 256) {
        *(float4*)(ws + i * 4) = *(const float4*)(W + i * 4);
    }
    for (int i = tid; i < 1024; i += 256) {
        int r  = i >> 5;
        int k4 = (i & 31) * 4;
        int gr = base + r;
        float4 v = make_float4(0.f, 0.f, 0.f, 0.f);
        if (gr < nrows) {
            v = *(const float4*)(X + (long long)gr * 128 + k4);
            float sc = scale[gr];
            v.x *= sc; v.y *= sc; v.z *= sc; v.w *= sc;
        }
        *(float4*)(xs + r * 128 + k4) = v;
    }
    __syncthreads();

    const int r0  = tid >> 5;
    const int col = (tid & 31) * 4;
    float4 a0 = make_float4(0.f,0.f,0.f,0.f);
    float4 a1 = a0, a2 = a0, a3 = a0;

    #pragma unroll 4
    for (int k = 0; k < 128; ++k) {
        float4 w = *(const float4*)(ws + k * 128 + col);
        float x0 = xs[(r0     ) * 128 + k];
        float x1 = xs[(r0 +  8) * 128 + k];
        float x2 = xs[(r0 + 16) * 128 + k];
        float x3 = xs[(r0 + 24) * 128 + k];
        a0.x += x0 * w.x; a0.y += x0 * w.y; a0.z += x0 * w.z; a0.w += x0 * w.w;
        a1.x += x1 * w.x; a1.y += x1 * w.y; a1.z += x1 * w.z; a1.w += x1 * w.w;
        a2.x += x2 * w.x; a2.y += x2 * w.y; a2.z += x2 * w.z; a2.w += x2 * w.w;
        a3.x += x3 * w.x; a3.y += x3 * w.y; a3.z += x3 * w.z; a3.w += x3 * w.w;
    }

    half4 h;
    int gr;
    gr = base + r0;
    if (gr < nrows) {
        h.x = __float2half(a0.x); h.y = __float2half(a0.y);
        h.z = __float2half(a0.z); h.w = __float2half(a0.w);
        *(half4*)(Y + (long long)gr * 128 + col) = h;
    }
    gr = base + r0 + 8;
    if (gr < nrows) {
        h.x = __float2half(a1.x); h.y = __float2half(a1.y);
        h.z = __float2half(a1.z); h.w = __float2half(a1.w);
        *(half4*)(Y + (long long)gr * 128 + col) = h;
    }
    gr = base + r0 + 16;
    if (gr < nrows) {
        h.x = __float2half(a2.x); h.y = __float2half(a2.y);
        h.z = __float2half(a2.z); h.w = __float2half(a2.w);
        *(half4*)(Y + (long long)gr * 128 + col) = h;
    }
    gr = base + r0 + 24;
    if (gr < nrows) {
        h.x = __float2half(a3.x); h.y = __float2half(a3.y);
        h.z = __float2half(a3.z); h.w = __float2half(a3.w);
        *(half4*)(Y + (long long)gr * 128 + col) = h;
    }
}

// G[n x 40] (fp16) = (H[n x 128] * scale[row]) @ Wp[128 x 40]
__global__ __launch_bounds__(256) void gemm40(
        const float* __restrict__ H, const float* __restrict__ scale,
        const float* __restrict__ Wp, __half* __restrict__ G, int n) {
    __shared__ float ws[128 * 40];   // 20 KB
    const int tid = threadIdx.x;
    for (int i = tid; i < 1280; i += 256) {
        *(float4*)(ws + i * 4) = *(const float4*)(Wp + i * 4);
    }
    __syncthreads();

    const int idx = blockIdx.x * 256 + tid;
    const int rg  = idx / 40;
    const int c   = idx - rg * 40;
    const int r0  = rg * 4;
    if (r0 >= n) return;

    const float* h = H + (long long)r0 * 128;

    if (r0 + 4 <= n) {
        float a0 = 0.f, a1 = 0.f, a2 = 0.f, a3 = 0.f;
        #pragma unroll 4
        for (int k = 0; k < 128; k += 4) {
            float4 x0 = *(const float4*)(h + k);
            float4 x1 = *(const float4*)(h + 128 + k);
            float4 x2 = *(const float4*)(h + 256 + k);
            float4 x3 = *(const float4*)(h + 384 + k);
            float w0 = ws[(k + 0) * 40 + c];
            float w1 = ws[(k + 1) * 40 + c];
            float w2 = ws[(k + 2) * 40 + c];
            float w3 = ws[(k + 3) * 40 + c];
            a0 += x0.x * w0 + x0.y * w1 + x0.z * w2 + x0.w * w3;
            a1 += x1.x * w0 + x1.y * w1 + x1.z * w2 + x1.w * w3;
            a2 += x2.x * w0 + x2.y * w1 + x2.z * w2 + x2.w * w3;
            a3 += x3.x * w0 + x3.y * w1 + x3.z * w2 + x3.w * w3;
        }
        G[(long long)(r0 + 0) * 40 + c] = __float2half(a0 * scale[r0 + 0]);
        G[(long long)(r0 + 1) * 40 + c] = __float2half(a1 * scale[r0 + 1]);
        G[(long long)(r0 + 2) * 40 + c] = __float2half(a2 * scale[r0 + 2]);
        G[(long long)(r0 + 3) * 40 + c] = __float2half(a3 * scale[r0 + 3]);
    } else {
        for (int r = r0; r < n; ++r) {
            const float* hr = H + (long long)r * 128;
            float a = 0.f;
            #pragma unroll 4
            for (int k = 0; k < 128; k += 4) {
                float4 x = *(const float4*)(hr + k);
                a += x.x * ws[(k + 0) * 40 + c] + x.y * ws[(k + 1) * 40 + c]
                   + x.z * ws[(k + 2) * 40 + c] + x.w * ws[(k + 3) * 40 + c];
            }
            G[(long long)r * 40 + c] = __float2half(a * scale[r]);
        }
    }
}

// 128-dim gather (fp16 in, fp32 out): out[node] = relu?((sum H[src]) * ni + b)
// 32 lanes per node (half4 = 8B per lane), 8-deep unroll for MLP.
__global__ __launch_bounds__(256) void gather_kernel(
        const __half* __restrict__ H, const int* __restrict__ row_ptr,
        const int* __restrict__ deg, const int* __restrict__ csr_src,
        const float* __restrict__ norm_in, const float* __restrict__ b,
        float* __restrict__ out, int n, int do_relu) {
    const int tid  = threadIdx.x;
    const int node = blockIdx.x * 8 + (tid >> 5);
    const int c    = (tid & 31) * 4;
    if (node >= n) return;

    const int start = row_ptr[node];
    const int cnt   = deg[node];
    float4 acc = make_float4(0.f, 0.f, 0.f, 0.f);

    int j = 0;
    for (; j + 8 <= cnt; j += 8) {
        int s0 = csr_src[start + j];
        int s1 = csr_src[start + j + 1];
        int s2 = csr_src[start + j + 2];
        int s3 = csr_src[start + j + 3];
        int s4 = csr_src[start + j + 4];
        int s5 = csr_src[start + j + 5];
        int s6 = csr_src[start + j + 6];
        int s7 = csr_src[start + j + 7];
        half4 v0 = *(const half4*)(H + (long long)s0 * 128 + c);
        half4 v1 = *(const half4*)(H + (long long)s1 * 128 + c);
        half4 v2 = *(const half4*)(H + (long long)s2 * 128 + c);
        half4 v3 = *(const half4*)(H + (long long)s3 * 128 + c);
        half4 v4 = *(const half4*)(H + (long long)s4 * 128 + c);
        half4 v5 = *(const half4*)(H + (long long)s5 * 128 + c);
        half4 v6 = *(const half4*)(H + (long long)s6 * 128 + c);
        half4 v7 = *(const half4*)(H + (long long)s7 * 128 + c);
        acc_half4(acc, v0); acc_half4(acc, v1); acc_half4(acc, v2); acc_half4(acc, v3);
        acc_half4(acc, v4); acc_half4(acc, v5); acc_half4(acc, v6); acc_half4(acc, v7);
    }
    for (; j + 4 <= cnt; j += 4) {
        int s0 = csr_src[start + j];
        int s1 = csr_src[start + j + 1];
        int s2 = csr_src[start + j + 2];
        int s3 = csr_src[start + j + 3];
        half4 v0 = *(const half4*)(H + (long long)s0 * 128 + c);
        half4 v1 = *(const half4*)(H + (long long)s1 * 128 + c);
        half4 v2 = *(const half4*)(H + (long long)s2 * 128 + c);
        half4 v3 = *(const half4*)(H + (long long)s3 * 128 + c);
        acc_half4(acc, v0); acc_half4(acc, v1); acc_half4(acc, v2); acc_half4(acc, v3);
    }
    for (; j < cnt; ++j) {
        int s0 = csr_src[start + j];
        half4 v0 = *(const half4*)(H + (long long)s0 * 128 + c);
        acc_half4(acc, v0);
    }

    float ni = norm_in[node];
    float4 bb = *(const float4*)(b + c);
    acc.x = acc.x * ni + bb.x;
    acc.y = acc.y * ni + bb.y;
    acc.z = acc.z * ni + bb.z;
    acc.w = acc.w * ni + bb.w;
    if (do_relu) {
        acc.x = fmaxf(acc.x, 0.f); acc.y = fmaxf(acc.y, 0.f);
        acc.z = fmaxf(acc.z, 0.f); acc.w = fmaxf(acc.w, 0.f);
    }
    *(float4*)(out + (long long)node * 128 + c) = acc;
}

// 40-dim gather (fp16 in, fp32 out): out[node] = (sum G[src]) * ni + b2p
// 10 threads per node (half4 = 8B each).
__global__ __launch_bounds__(256) void gather40_kernel(
        const __half* __restrict__ G, const int* __restrict__ row_ptr,
        const int* __restrict__ deg, const int* __restrict__ csr_src,
        const float* __restrict__ norm_in, const float* __restrict__ b2p,
        float* __restrict__ out, int n) {
    const int t = blockIdx.x * 256 + threadIdx.x;
    if (t >= n * 10) return;
    const int node = t / 10;
    const int c    = (t - node * 10) * 4;

    const int start = row_ptr[node];
    const int cnt   = deg[node];
    float4 acc = make_float4(0.f, 0.f, 0.f, 0.f);

    int j = 0;
    for (; j + 8 <= cnt; j += 8) {
        int s0 = csr_src[start + j];
        int s1 = csr_src[start + j + 1];
        int s2 = csr_src[start + j + 2];
        int s3 = csr_src[start + j + 3];
        int s4 = csr_src[start + j + 4];
        int s5 = csr_src[start + j + 5];
        int s6 = csr_src[start + j + 6];
        int s7 = csr_src[start + j + 7];
        half4 v0 = *(const half4*)(G + (long long)s0 * 40 + c);
        half4 v1 = *(const half4*)(G + (long long)s1 * 40 + c);
        half4 v2 = *(const half4*)(G + (long long)s2 * 40 + c);
        half4 v3 = *(const half4*)(G + (long long)s3 * 40 + c);
        half4 v4 = *(const half4*)(G + (long long)s4 * 40 + c);
        half4 v5 = *(const half4*)(G + (long long)s5 * 40 + c);
        half4 v6 = *(const half4*)(G + (long long)s6 * 40 + c);
        half4 v7 = *(const half4*)(G + (long long)s7 * 40 + c);
        acc_half4(acc, v0); acc_half4(acc, v1); acc_half4(acc, v2); acc_half4(acc, v3);
        acc_half4(acc, v4); acc_half4(acc, v5); acc_half4(acc, v6); acc_half4(acc, v7);
    }
    for (; j + 4 <= cnt; j += 4) {
        int s0 = csr_src[start + j];
        int s1 = csr_src[start + j + 1];
        int s2 = csr_src[start + j + 2];
        int s3 = csr_src[start + j + 3];
        half4 v0 = *(const half4*)(G + (long long)s0 * 40 + c);
        half4 v1 = *(const half4*)(G + (long long)s1 * 40 + c);
        half4 v2 = *(const half4*)(G + (long long)s2 * 40 + c);
        half4 v3 = *(const half4*)(G + (long long)s3 * 40 + c);
        acc_half4(acc, v0); acc_half4(acc, v1); acc_half4(acc, v2); acc_half4(acc, v3);
    }
    for (; j < cnt; ++j) {
        int s0 = csr_src[start + j];
        half4 v0 = *(const half4*)(G + (long long)s0 * 40 + c);
        acc_half4(acc, v0);
    }

    float ni = norm_in[node];
    float4 bb = *(const float4*)(b2p + c);
    acc.x = acc.x * ni + bb.x;
    acc.y = acc.y * ni + bb.y;
    acc.z = acc.z * ni + bb.z;
    acc.w = acc.w * ni + bb.w;
    *(float4*)(out + (long long)node * 40 + c) = acc;
}

extern "C" void kernel_launch(void* const* d_in, const int* in_sizes, int n_in,
                              void* d_out, int out_size, void* d_ws, size_t ws_size,
                              hipStream_t stream) {
    const float* x   = (const float*)d_in[0];
    const int*   ei  = (const int*)  d_in[1];
    const float* W1  = (const float*)d_in[2];
    const float* b1  = (const float*)d_in[3];
    const float* W2  = (const float*)d_in[4];
    const float* b2  = (const float*)d_in[5];
    const float* Wfc = (const float*)d_in[6];
    const float* bfc = (const float*)d_in[7];
    float* out = (float*)d_out;

    const int N = in_sizes[0] / 128;
    const int E = in_sizes[1] / 2;
    const int* src = ei;
    const int* dst = ei + E;

    const int B1 = (E + CHUNK - 1) / CHUNK;            // coarse blocks (391)
    const int n_counts = 2 * NB * B1;                   // 200192
    const int n_scan_blocks = (n_counts + SCAN_BLK - 1) / SCAN_BLK;

    char* p = (char*)d_ws;
    float* norm_out = (float*)p; p += (size_t)N * 4;
    float* norm_in  = (float*)p; p += (size_t)N * 4;
    float* bufA     = (float*)p; p += (size_t)N * 128 * 4;   // h1pre fp16, then G fp16
    float* bufB     = (float*)p; p += (size_t)N * 128 * 4;   // h1 fp32 (aliased early: partitions)
    int*   deg_in   = (int*)p;   p += (size_t)N * 4;
    int*   row_ptr  = (int*)p;   p += (size_t)N * 4;
    int*   csr_src  = (int*)p;   p += (size_t)E * 4;
    int*   counts   = (int*)p;   p += (size_t)n_counts * 4;
    int*   coff     = (int*)p;   p += (size_t)n_counts * 4;
    int*   aux      = (int*)p;   p += (size_t)((n_scan_blocks + 3) & ~3) * 4;
    float* W2p      = (float*)p; p += (size_t)128 * 40 * 4;
    float* b2p      = (float*)p; p += (size_t)64 * 4;

    // partition buffers alias bufB (consumed before gather writes h1 there)
    int* pdst   = (int*)bufB;
    int* psrc   = pdst + E;
    int* es_src = psrc + E;

    __half* h1pre = (__half*)bufA;   // N x 128 fp16 (25.6 MB < 51.2 MB slot)
    __half* G     = (__half*)bufA;   // N x 40  fp16 (reused after gather1)

    const int T = 256;

    // ---- CSR build + norms: zero per-edge global atomics ----
    count_coarse_kernel<<<B1, T, 0, stream>>>(src, dst, counts, E, B1);
    scan_block_kernel<<<n_scan_blocks, T, 0, stream>>>(counts, coff, aux, n_counts);
    scan_aux_kernel<<<1, 1024, 0, stream>>>(aux, n_scan_blocks);
    add_offsets_kernel<<<(n_counts + T - 1) / T, T, 0, stream>>>(coff, aux, n_counts);
    scatter_coarse_kernel<<<B1, T, 0, stream>>>(src, dst, coff, pdst, psrc, es_src, E, B1);
    fine_dst_kernel<<<NB, T, 0, stream>>>(pdst, psrc, coff, deg_in, norm_in,
                                          row_ptr, csr_src, N, B1);
    fine_src_kernel<<<NB, T, 0, stream>>>(es_src, coff, norm_out, N, E, B1);

    // fold layer2+FC weights
    fold_w2_kernel<<<(129 * 40 + T - 1) / T, T, 0, stream>>>(W2, Wfc, b2, bfc, W2p, b2p);

    const int gemm_grid   = (N + 31) / 32;
    const int gather_grid = (N + 7) / 8;

    // layer 0: h1 = relu(gather(Xn @ W1) * ni + b1)
    gemm128<<<gemm_grid, T, 0, stream>>>(x, norm_out, W1, h1pre, N);
    gather_kernel<<<gather_grid, T, 0, stream>>>(h1pre, row_ptr, deg_in, csr_src,
                                                 norm_in, b1, bufB, N, 1);
    // layer 1 + FC fused: out = gather((h1*no) @ W2p) * ni + b2p
    const int g40_grid = ((N + 3) / 4 * 40 + T - 1) / T;
    gemm40<<<g40_grid, T, 0, stream>>>(bufB, norm_out, W2p, G, N);
    gather40_kernel<<<((size_t)N * 10 + T - 1) / T, T, 0, stream>>>(
        G, row_ptr, deg_in, csr_src, norm_in, b2p, out, N);
}

// Round 7
// 376.646 us; speedup vs baseline: 15.7807x; 1.1229x over previous
//
#include <hip/hip_runtime.h>
#include <hip/hip_fp16.h>

// ---------------------------------------------------------------------------
// GCN: 2x GraphConv (norm='both') + FC.  fp32 math, fp16 gather intermediates.
// R2: CSR gather instead of atomic scatter (5943 -> 840 us).
// R3: LDS-staged fc, gather unroll-4 (840 -> 782 us).
// R4: atomic-free CSR fill (rank trick); fold layer2+FC (782 -> 585 us).
// R5: zero per-edge global atomics: 2-level counting sort (585 -> 503 us).
// R6: fp16 gather intermediates, halved gather bytes (503 -> 423 us).
// R7: (a) gemm128 -> MFMA bf16 hi/lo split (XhWh+XhWl+XlWh, ~fp19 input
//         precision; was 80 us LDS-issue-bound on the fp32 vector pipe).
//     (b) packed partition payloads: (dlocal<<17|src) u32 + src-local u16
//         -> scatter/fine traffic halved.
// ---------------------------------------------------------------------------

#define SCAN_BLK 1024   // elements per scan block
#define CHUNK    4096   // edges per coarse block
#define NB       256    // coarse buckets (node>>9; 100000>>9 = 195 max)

typedef __attribute__((ext_vector_type(8))) short bf16x8;
typedef __attribute__((ext_vector_type(4))) float f32x4;

struct __align__(8) half4 { __half x, y, z, w; };

__device__ __forceinline__ void acc_half4(float4& acc, const half4 v) {
    acc.x += __half2float(v.x);
    acc.y += __half2float(v.y);
    acc.z += __half2float(v.z);
    acc.w += __half2float(v.w);
}

__device__ __forceinline__ unsigned short f2bf(float f) {
    union { float f; unsigned u; } v; v.f = f;
    unsigned r = v.u + 0x7FFFu + ((v.u >> 16) & 1u);   // RNE
    return (unsigned short)(r >> 16);
}
__device__ __forceinline__ float bf2f(unsigned short h) {
    union { unsigned u; float f; } v; v.u = ((unsigned)h) << 16;
    return v.f;
}

// ---------------- generic scan (used for the 200K coarse-count array) -------
__global__ __launch_bounds__(256) void scan_block_kernel(
        const int* __restrict__ in, int* __restrict__ out, int* __restrict__ aux, int n) {
    __shared__ int sdata[256];
    const int tid = threadIdx.x;
    const int base = blockIdx.x * SCAN_BLK + tid * 4;
    int v0 = (base + 0 < n) ? in[base + 0] : 0;
    int v1 = (base + 1 < n) ? in[base + 1] : 0;
    int v2 = (base + 2 < n) ? in[base + 2] : 0;
    int v3 = (base + 3 < n) ? in[base + 3] : 0;
    int tot = v0 + v1 + v2 + v3;
    sdata[tid] = tot;
    __syncthreads();
    for (int off = 1; off < 256; off <<= 1) {
        int t = (tid >= off) ? sdata[tid - off] : 0;
        __syncthreads();
        sdata[tid] += t;
        __syncthreads();
    }
    int excl = sdata[tid] - tot;
    if (base + 0 < n) out[base + 0] = excl;
    if (base + 1 < n) out[base + 1] = excl + v0;
    if (base + 2 < n) out[base + 2] = excl + v0 + v1;
    if (base + 3 < n) out[base + 3] = excl + v0 + v1 + v2;
    if (tid == 255) aux[blockIdx.x] = sdata[255];
}

__global__ __launch_bounds__(1024) void scan_aux_kernel(int* __restrict__ aux, int nb) {
    __shared__ int sdata[1024];
    const int tid = threadIdx.x;
    int v = (tid < nb) ? aux[tid] : 0;
    sdata[tid] = v;
    __syncthreads();
    for (int off = 1; off < 1024; off <<= 1) {
        int t = (tid >= off) ? sdata[tid - off] : 0;
        __syncthreads();
        sdata[tid] += t;
        __syncthreads();
    }
    if (tid < nb) aux[tid] = sdata[tid] - v;   // exclusive
}

__global__ void add_offsets_kernel(int* __restrict__ arr, const int* __restrict__ aux, int n) {
    int i = blockIdx.x * blockDim.x + threadIdx.x;
    if (i < n) arr[i] += aux[i / SCAN_BLK];
}

// ------------- stage 1: coarse count (LDS histograms, plain stores) ---------
__global__ __launch_bounds__(256) void count_coarse_kernel(
        const int* __restrict__ src, const int* __restrict__ dst,
        int* __restrict__ counts, int E, int B1) {
    __shared__ int hd[NB], hs[NB];
    const int tid = threadIdx.x;
    hd[tid] = 0; hs[tid] = 0;
    __syncthreads();
    const int base = blockIdx.x * CHUNK;
    for (int i = tid; i < CHUNK; i += 256) {
        int e = base + i;
        if (e < E) {
            atomicAdd(&hd[((unsigned)dst[e]) >> 9], 1);
            atomicAdd(&hs[((unsigned)src[e]) >> 9], 1);
        }
    }
    __syncthreads();
    counts[tid * B1 + blockIdx.x]        = hd[tid];
    counts[(NB + tid) * B1 + blockIdx.x] = hs[tid];
}

// ------------- stage 2: partition edges by coarse bucket (LDS cursors) ------
// ppack[i] = (dst_local<<17) | src  (N < 2^17, dst_local < 512)
// es_loc[i] = src_local (u16)
__global__ __launch_bounds__(256) void scatter_coarse_kernel(
        const int* __restrict__ src, const int* __restrict__ dst,
        const int* __restrict__ coff,
        unsigned int* __restrict__ ppack, unsigned short* __restrict__ es_loc,
        int E, int B1) {
    __shared__ int cd[NB], cs[NB];
    const int tid = threadIdx.x;
    cd[tid] = coff[tid * B1 + blockIdx.x];
    cs[tid] = coff[(NB + tid) * B1 + blockIdx.x] - E;   // src section offset by E
    __syncthreads();
    const int base = blockIdx.x * CHUNK;
    for (int i = tid; i < CHUNK; i += 256) {
        int e = base + i;
        if (e < E) {
            int d = dst[e], s = src[e];
            int pd = atomicAdd(&cd[((unsigned)d) >> 9], 1);
            ppack[pd] = (((unsigned)d & 511u) << 17) | (unsigned)s;
            int ps = atomicAdd(&cs[((unsigned)s) >> 9], 1);
            es_loc[ps] = (unsigned short)(s & 511);
        }
    }
}

// ------------- stage 3a: per-bucket fine pass for dst ----------------------
__global__ __launch_bounds__(256) void fine_dst_kernel(
        const unsigned int* __restrict__ ppack, const int* __restrict__ coff,
        int* __restrict__ deg_in, float* __restrict__ norm_in,
        int* __restrict__ row_ptr, int* __restrict__ csr_src,
        int N_, int B1) {
    __shared__ int h[512];
    __shared__ int psum[256];
    const int tid = threadIdx.x;
    const int b = blockIdx.x;
    const int start = coff[b * B1];
    const int end   = coff[(b + 1) * B1];
    const int node0 = b * 512;

    h[tid] = 0; h[tid + 256] = 0;
    __syncthreads();
    for (int i = start + tid; i < end; i += 256)
        atomicAdd(&h[ppack[i] >> 17], 1);
    __syncthreads();

    int a0 = h[2 * tid], a1 = h[2 * tid + 1];
    int pair = a0 + a1;
    psum[tid] = pair;
    __syncthreads();
    for (int off = 1; off < 256; off <<= 1) {
        int t = (tid >= off) ? psum[tid - off] : 0;
        __syncthreads();
        psum[tid] += t;
        __syncthreads();
    }
    int base0 = psum[tid] - pair + start;

    int n0 = node0 + 2 * tid, n1 = n0 + 1;
    if (n0 < N_) {
        deg_in[n0]  = a0;
        row_ptr[n0] = base0;
        norm_in[n0] = rsqrtf((float)(a0 < 1 ? 1 : a0));
    }
    if (n1 < N_) {
        deg_in[n1]  = a1;
        row_ptr[n1] = base0 + a0;
        norm_in[n1] = rsqrtf((float)(a1 < 1 ? 1 : a1));
    }
    h[2 * tid]     = base0;
    h[2 * tid + 1] = base0 + a0;
    __syncthreads();

    for (int i = start + tid; i < end; i += 256) {
        unsigned int pk = ppack[i];
        int pos = atomicAdd(&h[pk >> 17], 1);
        csr_src[pos] = (int)(pk & 0x1FFFFu);
    }
}

// ------------- stage 3b: per-bucket fine pass for src (norm_out only) -------
__global__ __launch_bounds__(256) void fine_src_kernel(
        const unsigned short* __restrict__ es_loc, const int* __restrict__ coff,
        float* __restrict__ norm_out, int N_, int E, int B1) {
    __shared__ int h[512];
    const int tid = threadIdx.x;
    const int b = blockIdx.x;
    const int start = coff[(NB + b) * B1] - E;
    const int end   = (b == NB - 1) ? E : coff[(NB + b + 1) * B1] - E;
    const int node0 = b * 512;

    h[tid] = 0; h[tid + 256] = 0;
    __syncthreads();
    for (int i = start + tid; i < end; i += 256)
        atomicAdd(&h[es_loc[i]], 1);
    __syncthreads();

    int n0 = node0 + tid, n1 = n0 + 256;
    if (n0 < N_) { int d = h[tid];       norm_out[n0] = rsqrtf((float)(d < 1 ? 1 : d)); }
    if (n1 < N_) { int d = h[tid + 256]; norm_out[n1] = rsqrtf((float)(d < 1 ? 1 : d)); }
}

// W2p[128x40] = W2[128x128] @ Wfc[128x40];  b2p[40] = b2 @ Wfc + bfc
__global__ void fold_w2_kernel(const float* __restrict__ W2, const float* __restrict__ Wfc,
                               const float* __restrict__ b2, const float* __restrict__ bfc,
                               float* __restrict__ W2p, float* __restrict__ b2p) {
    int idx = blockIdx.x * blockDim.x + threadIdx.x;
    if (idx < 128 * 40) {
        int k = idx / 40, c = idx - (idx / 40) * 40;
        const float* w2row = W2 + k * 128;
        float a = 0.f;
        #pragma unroll 8
        for (int j = 0; j < 128; ++j) a += w2row[j] * Wfc[j * 40 + c];
        W2p[idx] = a;
    } else if (idx < 129 * 40) {
        int c = idx - 128 * 40;
        float a = bfc[c];
        #pragma unroll 8
        for (int j = 0; j < 128; ++j) a += b2[j] * Wfc[j * 40 + c];
        b2p[c] = a;
    }
}

// ---------------------------------------------------------------------------
// Y[nrows x 128] (fp16) = (X * scale[row]) @ W[128x128]  via MFMA bf16 split.
// X = Xh+Xl, W = Wh+Wl (bf16); Y ~= XhWh + XhWl + XlWh (rel err ~1.5e-5).
// Block: 256 thr = 4 waves; wave owns 32 rows (2 x 16-row MFMA tiles);
// block covers 128 rows. W staged once per block in fragment-ordered LDS.
// Layouts (HW-verified): A[m=lane&15][k=quad*8+j]; B[k=quad*8+j][n=lane&15];
// D col=lane&15, row=quad*4+reg.
// ---------------------------------------------------------------------------
__global__ __launch_bounds__(256, 2) void gemm128(
        const float* __restrict__ X, const float* __restrict__ scale,
        const float* __restrict__ W, __half* __restrict__ Y, int nrows) {
    __shared__ unsigned short wsh[128 * 128];   // 32 KB, frag-ordered bf16 hi
    __shared__ unsigned short wsl[128 * 128];   // 32 KB, frag-ordered bf16 lo
    const int tid = threadIdx.x;

    // stage + split W into fragment order: idx = ((t*4+q)*64 + l)*8 + j
    for (int i = tid; i < 4096; i += 256) {
        int k  = i >> 5;
        int n0 = (i & 31) * 4;
        float4 wv = *(const float4*)(W + k * 128 + n0);
        int q = k >> 5, j = k & 7, lb = ((k >> 3) & 3) * 16;
        int tcol = n0 >> 4;
        int base = ((tcol * 4 + q) * 64) * 8 + j;
        float vals[4] = {wv.x, wv.y, wv.z, wv.w};
        #pragma unroll
        for (int c = 0; c < 4; ++c) {
            int l = lb + ((n0 + c) & 15);
            unsigned short h = f2bf(vals[c]);
            wsh[base + l * 8] = h;
            wsl[base + l * 8] = f2bf(vals[c] - bf2f(h));
        }
    }
    __syncthreads();

    const int lane = tid & 63;
    const int w    = tid >> 6;
    const int m    = lane & 15;
    const int quad = lane >> 4;
    const int rowBase = blockIdx.x * 128 + w * 32;

    // load + scale + split A fragments (32 rows, K=128)
    bf16x8 Ah[2][4], Al[2][4];
    #pragma unroll
    for (int rt = 0; rt < 2; ++rt) {
        int r = rowBase + rt * 16 + m;
        float sc = (r < nrows) ? scale[r] : 0.f;
        const float* xr = X + (size_t)(r < nrows ? r : 0) * 128;
        #pragma unroll
        for (int q = 0; q < 4; ++q) {
            int k0 = q * 32 + quad * 8;
            float4 a = *(const float4*)(xr + k0);
            float4 bv = *(const float4*)(xr + k0 + 4);
            float v[8] = {a.x * sc, a.y * sc, a.z * sc, a.w * sc,
                          bv.x * sc, bv.y * sc, bv.z * sc, bv.w * sc};
            bf16x8 hi, lo;
            #pragma unroll
            for (int j = 0; j < 8; ++j) {
                unsigned short h = f2bf(v[j]);
                hi[j] = (short)h;
                lo[j] = (short)f2bf(v[j] - bf2f(h));
            }
            Ah[rt][q] = hi; Al[rt][q] = lo;
        }
    }

    f32x4 acc[2][8];
    #pragma unroll
    for (int rt = 0; rt < 2; ++rt)
        #pragma unroll
        for (int t = 0; t < 8; ++t)
            acc[rt][t] = (f32x4){0.f, 0.f, 0.f, 0.f};

    #pragma unroll
    for (int t = 0; t < 8; ++t) {
        #pragma unroll
        for (int q = 0; q < 4; ++q) {
            const int off = ((t * 4 + q) * 64 + lane) * 8;
            bf16x8 Bh = *(const bf16x8*)(wsh + off);
            bf16x8 Bl = *(const bf16x8*)(wsl + off);
            #pragma unroll
            for (int rt = 0; rt < 2; ++rt) {
                acc[rt][t] = __builtin_amdgcn_mfma_f32_16x16x32_bf16(Ah[rt][q], Bh, acc[rt][t], 0, 0, 0);
                acc[rt][t] = __builtin_amdgcn_mfma_f32_16x16x32_bf16(Ah[rt][q], Bl, acc[rt][t], 0, 0, 0);
                acc[rt][t] = __builtin_amdgcn_mfma_f32_16x16x32_bf16(Al[rt][q], Bh, acc[rt][t], 0, 0, 0);
            }
        }
    }

    #pragma unroll
    for (int rt = 0; rt < 2; ++rt) {
        int r0 = rowBase + rt * 16 + quad * 4;
        #pragma unroll
        for (int reg = 0; reg < 4; ++reg) {
            int r = r0 + reg;
            if (r >= nrows) continue;
            __half* yr = Y + (size_t)r * 128 + m;
            #pragma unroll
            for (int t = 0; t < 8; ++t)
                yr[t * 16] = __float2half(acc[rt][t][reg]);
        }
    }
}

// G[n x 40] (fp16) = (H[n x 128] * scale[row]) @ Wp[128 x 40]
__global__ __launch_bounds__(256) void gemm40(
        const float* __restrict__ H, const float* __restrict__ scale,
        const float* __restrict__ Wp, __half* __restrict__ G, int n) {
    __shared__ float ws[128 * 40];   // 20 KB
    const int tid = threadIdx.x;
    for (int i = tid; i < 1280; i += 256) {
        *(float4*)(ws + i * 4) = *(const float4*)(Wp + i * 4);
    }
    __syncthreads();

    const int idx = blockIdx.x * 256 + tid;
    const int rg  = idx / 40;
    const int c   = idx - rg * 40;
    const int r0  = rg * 4;
    if (r0 >= n) return;

    const float* h = H + (long long)r0 * 128;

    if (r0 + 4 <= n) {
        float a0 = 0.f, a1 = 0.f, a2 = 0.f, a3 = 0.f;
        #pragma unroll 4
        for (int k = 0; k < 128; k += 4) {
            float4 x0 = *(const float4*)(h + k);
            float4 x1 = *(const float4*)(h + 128 + k);
            float4 x2 = *(const float4*)(h + 256 + k);
            float4 x3 = *(const float4*)(h + 384 + k);
            float w0 = ws[(k + 0) * 40 + c];
            float w1 = ws[(k + 1) * 40 + c];
            float w2 = ws[(k + 2) * 40 + c];
            float w3 = ws[(k + 3) * 40 + c];
            a0 += x0.x * w0 + x0.y * w1 + x0.z * w2 + x0.w * w3;
            a1 += x1.x * w0 + x1.y * w1 + x1.z * w2 + x1.w * w3;
            a2 += x2.x * w0 + x2.y * w1 + x2.z * w2 + x2.w * w3;
            a3 += x3.x * w0 + x3.y * w1 + x3.z * w2 + x3.w * w3;
        }
        G[(long long)(r0 + 0) * 40 + c] = __float2half(a0 * scale[r0 + 0]);
        G[(long long)(r0 + 1) * 40 + c] = __float2half(a1 * scale[r0 + 1]);
        G[(long long)(r0 + 2) * 40 + c] = __float2half(a2 * scale[r0 + 2]);
        G[(long long)(r0 + 3) * 40 + c] = __float2half(a3 * scale[r0 + 3]);
    } else {
        for (int r = r0; r < n; ++r) {
            const float* hr = H + (long long)r * 128;
            float a = 0.f;
            #pragma unroll 4
            for (int k = 0; k < 128; k += 4) {
                float4 x = *(const float4*)(hr + k);
                a += x.x * ws[(k + 0) * 40 + c] + x.y * ws[(k + 1) * 40 + c]
                   + x.z * ws[(k + 2) * 40 + c] + x.w * ws[(k + 3) * 40 + c];
            }
            G[(long long)r * 40 + c] = __float2half(a * scale[r]);
        }
    }
}

// 128-dim gather (fp16 in, fp32 out): out[node] = relu?((sum H[src]) * ni + b)
__global__ __launch_bounds__(256) void gather_kernel(
        const __half* __restrict__ H, const int* __restrict__ row_ptr,
        const int* __restrict__ deg, const int* __restrict__ csr_src,
        const float* __restrict__ norm_in, const float* __restrict__ b,
        float* __restrict__ out, int n, int do_relu) {
    const int tid  = threadIdx.x;
    const int node = blockIdx.x * 8 + (tid >> 5);
    const int c    = (tid & 31) * 4;
    if (node >= n) return;

    const int start = row_ptr[node];
    const int cnt   = deg[node];
    float4 acc = make_float4(0.f, 0.f, 0.f, 0.f);

    int j = 0;
    for (; j + 8 <= cnt; j += 8) {
        int s0 = csr_src[start + j];
        int s1 = csr_src[start + j + 1];
        int s2 = csr_src[start + j + 2];
        int s3 = csr_src[start + j + 3];
        int s4 = csr_src[start + j + 4];
        int s5 = csr_src[start + j + 5];
        int s6 = csr_src[start + j + 6];
        int s7 = csr_src[start + j + 7];
        half4 v0 = *(const half4*)(H + (long long)s0 * 128 + c);
        half4 v1 = *(const half4*)(H + (long long)s1 * 128 + c);
        half4 v2 = *(const half4*)(H + (long long)s2 * 128 + c);
        half4 v3 = *(const half4*)(H + (long long)s3 * 128 + c);
        half4 v4 = *(const half4*)(H + (long long)s4 * 128 + c);
        half4 v5 = *(const half4*)(H + (long long)s5 * 128 + c);
        half4 v6 = *(const half4*)(H + (long long)s6 * 128 + c);
        half4 v7 = *(const half4*)(H + (long long)s7 * 128 + c);
        acc_half4(acc, v0); acc_half4(acc, v1); acc_half4(acc, v2); acc_half4(acc, v3);
        acc_half4(acc, v4); acc_half4(acc, v5); acc_half4(acc, v6); acc_half4(acc, v7);
    }
    for (; j + 4 <= cnt; j += 4) {
        int s0 = csr_src[start + j];
        int s1 = csr_src[start + j + 1];
        int s2 = csr_src[start + j + 2];
        int s3 = csr_src[start + j + 3];
        half4 v0 = *(const half4*)(H + (long long)s0 * 128 + c);
        half4 v1 = *(const half4*)(H + (long long)s1 * 128 + c);
        half4 v2 = *(const half4*)(H + (long long)s2 * 128 + c);
        half4 v3 = *(const half4*)(H + (long long)s3 * 128 + c);
        acc_half4(acc, v0); acc_half4(acc, v1); acc_half4(acc, v2); acc_half4(acc, v3);
    }
    for (; j < cnt; ++j) {
        int s0 = csr_src[start + j];
        half4 v0 = *(const half4*)(H + (long long)s0 * 128 + c);
        acc_half4(acc, v0);
    }

    float ni = norm_in[node];
    float4 bb = *(const float4*)(b + c);
    acc.x = acc.x * ni + bb.x;
    acc.y = acc.y * ni + bb.y;
    acc.z = acc.z * ni + bb.z;
    acc.w = acc.w * ni + bb.w;
    if (do_relu) {
        acc.x = fmaxf(acc.x, 0.f); acc.y = fmaxf(acc.y, 0.f);
        acc.z = fmaxf(acc.z, 0.f); acc.w = fmaxf(acc.w, 0.f);
    }
    *(float4*)(out + (long long)node * 128 + c) = acc;
}

// 40-dim gather (fp16 in, fp32 out): out[node] = (sum G[src]) * ni + b2p
__global__ __launch_bounds__(256) void gather40_kernel(
        const __half* __restrict__ G, const int* __restrict__ row_ptr,
        const int* __restrict__ deg, const int* __restrict__ csr_src,
        const float* __restrict__ norm_in, const float* __restrict__ b2p,
        float* __restrict__ out, int n) {
    const int t = blockIdx.x * 256 + threadIdx.x;
    if (t >= n * 10) return;
    const int node = t / 10;
    const int c    = (t - node * 10) * 4;

    const int start = row_ptr[node];
    const int cnt   = deg[node];
    float4 acc = make_float4(0.f, 0.f, 0.f, 0.f);

    int j = 0;
    for (; j + 8 <= cnt; j += 8) {
        int s0 = csr_src[start + j];
        int s1 = csr_src[start + j + 1];
        int s2 = csr_src[start + j + 2];
        int s3 = csr_src[start + j + 3];
        int s4 = csr_src[start + j + 4];
        int s5 = csr_src[start + j + 5];
        int s6 = csr_src[start + j + 6];
        int s7 = csr_src[start + j + 7];
        half4 v0 = *(const half4*)(G + (long long)s0 * 40 + c);
        half4 v1 = *(const half4*)(G + (long long)s1 * 40 + c);
        half4 v2 = *(const half4*)(G + (long long)s2 * 40 + c);
        half4 v3 = *(const half4*)(G + (long long)s3 * 40 + c);
        half4 v4 = *(const half4*)(G + (long long)s4 * 40 + c);
        half4 v5 = *(const half4*)(G + (long long)s5 * 40 + c);
        half4 v6 = *(const half4*)(G + (long long)s6 * 40 + c);
        half4 v7 = *(const half4*)(G + (long long)s7 * 40 + c);
        acc_half4(acc, v0); acc_half4(acc, v1); acc_half4(acc, v2); acc_half4(acc, v3);
        acc_half4(acc, v4); acc_half4(acc, v5); acc_half4(acc, v6); acc_half4(acc, v7);
    }
    for (; j + 4 <= cnt; j += 4) {
        int s0 = csr_src[start + j];
        int s1 = csr_src[start + j + 1];
        int s2 = csr_src[start + j + 2];
        int s3 = csr_src[start + j + 3];
        half4 v0 = *(const half4*)(G + (long long)s0 * 40 + c);
        half4 v1 = *(const half4*)(G + (long long)s1 * 40 + c);
        half4 v2 = *(const half4*)(G + (long long)s2 * 40 + c);
        half4 v3 = *(const half4*)(G + (long long)s3 * 40 + c);
        acc_half4(acc, v0); acc_half4(acc, v1); acc_half4(acc, v2); acc_half4(acc, v3);
    }
    for (; j < cnt; ++j) {
        int s0 = csr_src[start + j];
        half4 v0 = *(const half4*)(G + (long long)s0 * 40 + c);
        acc_half4(acc, v0);
    }

    float ni = norm_in[node];
    float4 bb = *(const float4*)(b2p + c);
    acc.x = acc.x * ni + bb.x;
    acc.y = acc.y * ni + bb.y;
    acc.z = acc.z * ni + bb.z;
    acc.w = acc.w * ni + bb.w;
    *(float4*)(out + (long long)node * 40 + c) = acc;
}

extern "C" void kernel_launch(void* const* d_in, const int* in_sizes, int n_in,
                              void* d_out, int out_size, void* d_ws, size_t ws_size,
                              hipStream_t stream) {
    const float* x   = (const float*)d_in[0];
    const int*   ei  = (const int*)  d_in[1];
    const float* W1  = (const float*)d_in[2];
    const float* b1  = (const float*)d_in[3];
    const float* W2  = (const float*)d_in[4];
    const float* b2  = (const float*)d_in[5];
    const float* Wfc = (const float*)d_in[6];
    const float* bfc = (const float*)d_in[7];
    float* out = (float*)d_out;

    const int N = in_sizes[0] / 128;
    const int E = in_sizes[1] / 2;
    const int* src = ei;
    const int* dst = ei + E;

    const int B1 = (E + CHUNK - 1) / CHUNK;            // coarse blocks (391)
    const int n_counts = 2 * NB * B1;                   // 200192
    const int n_scan_blocks = (n_counts + SCAN_BLK - 1) / SCAN_BLK;

    char* p = (char*)d_ws;
    float* norm_out = (float*)p; p += (size_t)N * 4;
    float* norm_in  = (float*)p; p += (size_t)N * 4;
    float* bufA     = (float*)p; p += (size_t)N * 128 * 4;   // h1pre fp16, then G fp16
    float* bufB     = (float*)p; p += (size_t)N * 128 * 4;   // h1 fp32 (aliased early: partitions)
    int*   deg_in   = (int*)p;   p += (size_t)N * 4;
    int*   row_ptr  = (int*)p;   p += (size_t)N * 4;
    int*   csr_src  = (int*)p;   p += (size_t)E * 4;
    int*   counts   = (int*)p;   p += (size_t)n_counts * 4;
    int*   coff     = (int*)p;   p += (size_t)n_counts * 4;
    int*   aux      = (int*)p;   p += (size_t)((n_scan_blocks + 3) & ~3) * 4;
    float* W2p      = (float*)p; p += (size_t)128 * 40 * 4;
    float* b2p      = (float*)p; p += (size_t)64 * 4;

    // partition buffers alias bufB (consumed before gather writes h1 there)
    unsigned int*   ppack  = (unsigned int*)bufB;               // E x u32
    unsigned short* es_loc = (unsigned short*)(ppack + E);      // E x u16

    __half* h1pre = (__half*)bufA;   // N x 128 fp16
    __half* G     = (__half*)bufA;   // N x 40  fp16 (reused after gather1)

    const int T = 256;

    // ---- CSR build + norms: zero per-edge global atomics ----
    count_coarse_kernel<<<B1, T, 0, stream>>>(src, dst, counts, E, B1);
    scan_block_kernel<<<n_scan_blocks, T, 0, stream>>>(counts, coff, aux, n_counts);
    scan_aux_kernel<<<1, 1024, 0, stream>>>(aux, n_scan_blocks);
    add_offsets_kernel<<<(n_counts + T - 1) / T, T, 0, stream>>>(coff, aux, n_counts);
    scatter_coarse_kernel<<<B1, T, 0, stream>>>(src, dst, coff, ppack, es_loc, E, B1);
    fine_dst_kernel<<<NB, T, 0, stream>>>(ppack, coff, deg_in, norm_in,
                                          row_ptr, csr_src, N, B1);
    fine_src_kernel<<<NB, T, 0, stream>>>(es_loc, coff, norm_out, N, E, B1);

    // fold layer2+FC weights
    fold_w2_kernel<<<(129 * 40 + T - 1) / T, T, 0, stream>>>(W2, Wfc, b2, bfc, W2p, b2p);

    // layer 0: h1 = relu(gather(Xn @ W1) * ni + b1)   [MFMA bf16-split GEMM]
    const int gemm_grid = (N + 127) / 128;
    gemm128<<<gemm_grid, T, 0, stream>>>(x, norm_out, W1, h1pre, N);
    const int gather_grid = (N + 7) / 8;
    gather_kernel<<<gather_grid, T, 0, stream>>>(h1pre, row_ptr, deg_in, csr_src,
                                                 norm_in, b1, bufB, N, 1);
    // layer 1 + FC fused: out = gather((h1*no) @ W2p) * ni + b2p
    const int g40_grid = ((N + 3) / 4 * 40 + T - 1) / T;
    gemm40<<<g40_grid, T, 0, stream>>>(bufB, norm_out, W2p, G, N);
    gather40_kernel<<<((size_t)N * 10 + T - 1) / T, T, 0, stream>>>(
        G, row_ptr, deg_in, csr_src, norm_in, b2p, out, N);
}

// Round 8
// 325.079 us; speedup vs baseline: 18.2839x; 1.1586x over previous
//
#include <hip/hip_runtime.h>
#include <hip/hip_fp16.h>

// ---------------------------------------------------------------------------
// GCN: 2x GraphConv (norm='both') + FC.  fp32 math, fp16 intermediates.
// R2: CSR gather instead of atomic scatter (5943 -> 840 us).
// R3: LDS-staged fc, gather unroll-4 (840 -> 782 us).
// R4: atomic-free CSR fill (rank trick); fold layer2+FC (782 -> 585 us).
// R5: zero per-edge global atomics: 2-level counting sort (585 -> 503 us).
// R6: fp16 gather intermediates, halved gather bytes (503 -> 423 us).
// R7: MFMA bf16 hi/lo split gemm128; packed partition payloads (423 -> 377).
// R8: (a) gemm40 -> MFMA (was 71 us: 10x redundant global-load issue +
//         2.4M LDS bank-conflict cycles on stride-40 reads). N padded to 48,
//         same frag-ordered hi/lo LDS structure as gemm128.
//     (b) h1 stored fp16 (only consumer is gemm40's bf16-split A-path):
//         halves gather1 WRITE and gemm40 FETCH.
// ---------------------------------------------------------------------------

#define SCAN_BLK 1024   // elements per scan block
#define CHUNK    4096   // edges per coarse block
#define NB       256    // coarse buckets (node>>9; 100000>>9 = 195 max)

typedef __attribute__((ext_vector_type(8))) short bf16x8;
typedef __attribute__((ext_vector_type(4))) float f32x4;

struct __align__(8) half4 { __half x, y, z, w; };

__device__ __forceinline__ void acc_half4(float4& acc, const half4 v) {
    acc.x += __half2float(v.x);
    acc.y += __half2float(v.y);
    acc.z += __half2float(v.z);
    acc.w += __half2float(v.w);
}

__device__ __forceinline__ unsigned short f2bf(float f) {
    union { float f; unsigned u; } v; v.f = f;
    unsigned r = v.u + 0x7FFFu + ((v.u >> 16) & 1u);   // RNE
    return (unsigned short)(r >> 16);
}
__device__ __forceinline__ float bf2f(unsigned short h) {
    union { unsigned u; float f; } v; v.u = ((unsigned)h) << 16;
    return v.f;
}

// ---------------- generic scan (used for the 200K coarse-count array) -------
__global__ __launch_bounds__(256) void scan_block_kernel(
        const int* __restrict__ in, int* __restrict__ out, int* __restrict__ aux, int n) {
    __shared__ int sdata[256];
    const int tid = threadIdx.x;
    const int base = blockIdx.x * SCAN_BLK + tid * 4;
    int v0 = (base + 0 < n) ? in[base + 0] : 0;
    int v1 = (base + 1 < n) ? in[base + 1] : 0;
    int v2 = (base + 2 < n) ? in[base + 2] : 0;
    int v3 = (base + 3 < n) ? in[base + 3] : 0;
    int tot = v0 + v1 + v2 + v3;
    sdata[tid] = tot;
    __syncthreads();
    for (int off = 1; off < 256; off <<= 1) {
        int t = (tid >= off) ? sdata[tid - off] : 0;
        __syncthreads();
        sdata[tid] += t;
        __syncthreads();
    }
    int excl = sdata[tid] - tot;
    if (base + 0 < n) out[base + 0] = excl;
    if (base + 1 < n) out[base + 1] = excl + v0;
    if (base + 2 < n) out[base + 2] = excl + v0 + v1;
    if (base + 3 < n) out[base + 3] = excl + v0 + v1 + v2;
    if (tid == 255) aux[blockIdx.x] = sdata[255];
}

__global__ __launch_bounds__(1024) void scan_aux_kernel(int* __restrict__ aux, int nb) {
    __shared__ int sdata[1024];
    const int tid = threadIdx.x;
    int v = (tid < nb) ? aux[tid] : 0;
    sdata[tid] = v;
    __syncthreads();
    for (int off = 1; off < 1024; off <<= 1) {
        int t = (tid >= off) ? sdata[tid - off] : 0;
        __syncthreads();
        sdata[tid] += t;
        __syncthreads();
    }
    if (tid < nb) aux[tid] = sdata[tid] - v;   // exclusive
}

__global__ void add_offsets_kernel(int* __restrict__ arr, const int* __restrict__ aux, int n) {
    int i = blockIdx.x * blockDim.x + threadIdx.x;
    if (i < n) arr[i] += aux[i / SCAN_BLK];
}

// ------------- stage 1: coarse count (LDS histograms, plain stores) ---------
__global__ __launch_bounds__(256) void count_coarse_kernel(
        const int* __restrict__ src, const int* __restrict__ dst,
        int* __restrict__ counts, int E, int B1) {
    __shared__ int hd[NB], hs[NB];
    const int tid = threadIdx.x;
    hd[tid] = 0; hs[tid] = 0;
    __syncthreads();
    const int base = blockIdx.x * CHUNK;
    for (int i = tid; i < CHUNK; i += 256) {
        int e = base + i;
        if (e < E) {
            atomicAdd(&hd[((unsigned)dst[e]) >> 9], 1);
            atomicAdd(&hs[((unsigned)src[e]) >> 9], 1);
        }
    }
    __syncthreads();
    counts[tid * B1 + blockIdx.x]        = hd[tid];
    counts[(NB + tid) * B1 + blockIdx.x] = hs[tid];
}

// ------------- stage 2: partition edges by coarse bucket (LDS cursors) ------
// ppack[i] = (dst_local<<17) | src  (N < 2^17, dst_local < 512)
// es_loc[i] = src_local (u16)
__global__ __launch_bounds__(256) void scatter_coarse_kernel(
        const int* __restrict__ src, const int* __restrict__ dst,
        const int* __restrict__ coff,
        unsigned int* __restrict__ ppack, unsigned short* __restrict__ es_loc,
        int E, int B1) {
    __shared__ int cd[NB], cs[NB];
    const int tid = threadIdx.x;
    cd[tid] = coff[tid * B1 + blockIdx.x];
    cs[tid] = coff[(NB + tid) * B1 + blockIdx.x] - E;   // src section offset by E
    __syncthreads();
    const int base = blockIdx.x * CHUNK;
    for (int i = tid; i < CHUNK; i += 256) {
        int e = base + i;
        if (e < E) {
            int d = dst[e], s = src[e];
            int pd = atomicAdd(&cd[((unsigned)d) >> 9], 1);
            ppack[pd] = (((unsigned)d & 511u) << 17) | (unsigned)s;
            int ps = atomicAdd(&cs[((unsigned)s) >> 9], 1);
            es_loc[ps] = (unsigned short)(s & 511);
        }
    }
}

// ------------- stage 3a: per-bucket fine pass for dst ----------------------
__global__ __launch_bounds__(256) void fine_dst_kernel(
        const unsigned int* __restrict__ ppack, const int* __restrict__ coff,
        int* __restrict__ deg_in, float* __restrict__ norm_in,
        int* __restrict__ row_ptr, int* __restrict__ csr_src,
        int N_, int B1) {
    __shared__ int h[512];
    __shared__ int psum[256];
    const int tid = threadIdx.x;
    const int b = blockIdx.x;
    const int start = coff[b * B1];
    const int end   = coff[(b + 1) * B1];
    const int node0 = b * 512;

    h[tid] = 0; h[tid + 256] = 0;
    __syncthreads();
    for (int i = start + tid; i < end; i += 256)
        atomicAdd(&h[ppack[i] >> 17], 1);
    __syncthreads();

    int a0 = h[2 * tid], a1 = h[2 * tid + 1];
    int pair = a0 + a1;
    psum[tid] = pair;
    __syncthreads();
    for (int off = 1; off < 256; off <<= 1) {
        int t = (tid >= off) ? psum[tid - off] : 0;
        __syncthreads();
        psum[tid] += t;
        __syncthreads();
    }
    int base0 = psum[tid] - pair + start;

    int n0 = node0 + 2 * tid, n1 = n0 + 1;
    if (n0 < N_) {
        deg_in[n0]  = a0;
        row_ptr[n0] = base0;
        norm_in[n0] = rsqrtf((float)(a0 < 1 ? 1 : a0));
    }
    if (n1 < N_) {
        deg_in[n1]  = a1;
        row_ptr[n1] = base0 + a0;
        norm_in[n1] = rsqrtf((float)(a1 < 1 ? 1 : a1));
    }
    h[2 * tid]     = base0;
    h[2 * tid + 1] = base0 + a0;
    __syncthreads();

    for (int i = start + tid; i < end; i += 256) {
        unsigned int pk = ppack[i];
        int pos = atomicAdd(&h[pk >> 17], 1);
        csr_src[pos] = (int)(pk & 0x1FFFFu);
    }
}

// ------------- stage 3b: per-bucket fine pass for src (norm_out only) -------
__global__ __launch_bounds__(256) void fine_src_kernel(
        const unsigned short* __restrict__ es_loc, const int* __restrict__ coff,
        float* __restrict__ norm_out, int N_, int E, int B1) {
    __shared__ int h[512];
    const int tid = threadIdx.x;
    const int b = blockIdx.x;
    const int start = coff[(NB + b) * B1] - E;
    const int end   = (b == NB - 1) ? E : coff[(NB + b + 1) * B1] - E;
    const int node0 = b * 512;

    h[tid] = 0; h[tid + 256] = 0;
    __syncthreads();
    for (int i = start + tid; i < end; i += 256)
        atomicAdd(&h[es_loc[i]], 1);
    __syncthreads();

    int n0 = node0 + tid, n1 = n0 + 256;
    if (n0 < N_) { int d = h[tid];       norm_out[n0] = rsqrtf((float)(d < 1 ? 1 : d)); }
    if (n1 < N_) { int d = h[tid + 256]; norm_out[n1] = rsqrtf((float)(d < 1 ? 1 : d)); }
}

// W2p[128x40] = W2[128x128] @ Wfc[128x40];  b2p[40] = b2 @ Wfc + bfc
__global__ void fold_w2_kernel(const float* __restrict__ W2, const float* __restrict__ Wfc,
                               const float* __restrict__ b2, const float* __restrict__ bfc,
                               float* __restrict__ W2p, float* __restrict__ b2p) {
    int idx = blockIdx.x * blockDim.x + threadIdx.x;
    if (idx < 128 * 40) {
        int k = idx / 40, c = idx - (idx / 40) * 40;
        const float* w2row = W2 + k * 128;
        float a = 0.f;
        #pragma unroll 8
        for (int j = 0; j < 128; ++j) a += w2row[j] * Wfc[j * 40 + c];
        W2p[idx] = a;
    } else if (idx < 129 * 40) {
        int c = idx - 128 * 40;
        float a = bfc[c];
        #pragma unroll 8
        for (int j = 0; j < 128; ++j) a += b2[j] * Wfc[j * 40 + c];
        b2p[c] = a;
    }
}

// ---------------------------------------------------------------------------
// Y[nrows x 128] (fp16) = (X * scale[row]) @ W[128x128]  via MFMA bf16 split.
// ---------------------------------------------------------------------------
__global__ __launch_bounds__(256, 2) void gemm128(
        const float* __restrict__ X, const float* __restrict__ scale,
        const float* __restrict__ W, __half* __restrict__ Y, int nrows) {
    __shared__ unsigned short wsh[128 * 128];   // 32 KB, frag-ordered bf16 hi
    __shared__ unsigned short wsl[128 * 128];   // 32 KB, frag-ordered bf16 lo
    const int tid = threadIdx.x;

    for (int i = tid; i < 4096; i += 256) {
        int k  = i >> 5;
        int n0 = (i & 31) * 4;
        float4 wv = *(const float4*)(W + k * 128 + n0);
        int q = k >> 5, j = k & 7, lb = ((k >> 3) & 3) * 16;
        int tcol = n0 >> 4;
        int base = ((tcol * 4 + q) * 64) * 8 + j;
        float vals[4] = {wv.x, wv.y, wv.z, wv.w};
        #pragma unroll
        for (int c = 0; c < 4; ++c) {
            int l = lb + ((n0 + c) & 15);
            unsigned short h = f2bf(vals[c]);
            wsh[base + l * 8] = h;
            wsl[base + l * 8] = f2bf(vals[c] - bf2f(h));
        }
    }
    __syncthreads();

    const int lane = tid & 63;
    const int w    = tid >> 6;
    const int m    = lane & 15;
    const int quad = lane >> 4;
    const int rowBase = blockIdx.x * 128 + w * 32;

    bf16x8 Ah[2][4], Al[2][4];
    #pragma unroll
    for (int rt = 0; rt < 2; ++rt) {
        int r = rowBase + rt * 16 + m;
        float sc = (r < nrows) ? scale[r] : 0.f;
        const float* xr = X + (size_t)(r < nrows ? r : 0) * 128;
        #pragma unroll
        for (int q = 0; q < 4; ++q) {
            int k0 = q * 32 + quad * 8;
            float4 a = *(const float4*)(xr + k0);
            float4 bv = *(const float4*)(xr + k0 + 4);
            float v[8] = {a.x * sc, a.y * sc, a.z * sc, a.w * sc,
                          bv.x * sc, bv.y * sc, bv.z * sc, bv.w * sc};
            bf16x8 hi, lo;
            #pragma unroll
            for (int j = 0; j < 8; ++j) {
                unsigned short h = f2bf(v[j]);
                hi[j] = (short)h;
                lo[j] = (short)f2bf(v[j] - bf2f(h));
            }
            Ah[rt][q] = hi; Al[rt][q] = lo;
        }
    }

    f32x4 acc[2][8];
    #pragma unroll
    for (int rt = 0; rt < 2; ++rt)
        #pragma unroll
        for (int t = 0; t < 8; ++t)
            acc[rt][t] = (f32x4){0.f, 0.f, 0.f, 0.f};

    #pragma unroll
    for (int t = 0; t < 8; ++t) {
        #pragma unroll
        for (int q = 0; q < 4; ++q) {
            const int off = ((t * 4 + q) * 64 + lane) * 8;
            bf16x8 Bh = *(const bf16x8*)(wsh + off);
            bf16x8 Bl = *(const bf16x8*)(wsl + off);
            #pragma unroll
            for (int rt = 0; rt < 2; ++rt) {
                acc[rt][t] = __builtin_amdgcn_mfma_f32_16x16x32_bf16(Ah[rt][q], Bh, acc[rt][t], 0, 0, 0);
                acc[rt][t] = __builtin_amdgcn_mfma_f32_16x16x32_bf16(Ah[rt][q], Bl, acc[rt][t], 0, 0, 0);
                acc[rt][t] = __builtin_amdgcn_mfma_f32_16x16x32_bf16(Al[rt][q], Bh, acc[rt][t], 0, 0, 0);
            }
        }
    }

    #pragma unroll
    for (int rt = 0; rt < 2; ++rt) {
        int r0 = rowBase + rt * 16 + quad * 4;
        #pragma unroll
        for (int reg = 0; reg < 4; ++reg) {
            int r = r0 + reg;
            if (r >= nrows) continue;
            __half* yr = Y + (size_t)r * 128 + m;
            #pragma unroll
            for (int t = 0; t < 8; ++t)
                yr[t * 16] = __float2half(acc[rt][t][reg]);
        }
    }
}

// ---------------------------------------------------------------------------
// G[n x 40] (fp16) = (H[n x 128 fp16] * scale[row]) @ Wp[128 x 40]
// MFMA bf16 hi/lo split; N padded to 48 (3 column tiles), cols >= 40 dropped.
// ---------------------------------------------------------------------------
__global__ __launch_bounds__(256, 2) void gemm40(
        const __half* __restrict__ H, const float* __restrict__ scale,
        const float* __restrict__ Wp, __half* __restrict__ G, int n) {
    __shared__ unsigned short wsh[48 * 128];   // 12 KB, frag-ordered bf16 hi
    __shared__ unsigned short wsl[48 * 128];   // 12 KB, frag-ordered bf16 lo
    const int tid = threadIdx.x;

    // stage + split Wp (pad cols 40..47 with zeros), fragment order
    for (int i = tid; i < 6144; i += 256) {
        int k  = i / 48;        // 0..127
        int nn = i - k * 48;    // 0..47
        float v = (nn < 40) ? Wp[k * 40 + nn] : 0.f;
        int t = nn >> 4, q = k >> 5, j = k & 7;
        int l = ((k >> 3) & 3) * 16 + (nn & 15);
        int base = ((t * 4 + q) * 64 + l) * 8 + j;
        unsigned short h = f2bf(v);
        wsh[base] = h;
        wsl[base] = f2bf(v - bf2f(h));
    }
    __syncthreads();

    const int lane = tid & 63;
    const int w    = tid >> 6;
    const int m    = lane & 15;
    const int quad = lane >> 4;
    const int rowBase = blockIdx.x * 128 + w * 32;

    // A fragments from fp16 H, scaled, split to bf16 hi/lo
    bf16x8 Ah[2][4], Al[2][4];
    #pragma unroll
    for (int rt = 0; rt < 2; ++rt) {
        int r = rowBase + rt * 16 + m;
        float sc = (r < n) ? scale[r] : 0.f;
        const __half* xr = H + (size_t)(r < n ? r : 0) * 128;
        #pragma unroll
        for (int q = 0; q < 4; ++q) {
            int k0 = q * 32 + quad * 8;
            half4 a = *(const half4*)(xr + k0);
            half4 bv = *(const half4*)(xr + k0 + 4);
            float v[8] = {__half2float(a.x) * sc, __half2float(a.y) * sc,
                          __half2float(a.z) * sc, __half2float(a.w) * sc,
                          __half2float(bv.x) * sc, __half2float(bv.y) * sc,
                          __half2float(bv.z) * sc, __half2float(bv.w) * sc};
            bf16x8 hi, lo;
            #pragma unroll
            for (int j = 0; j < 8; ++j) {
                unsigned short h = f2bf(v[j]);
                hi[j] = (short)h;
                lo[j] = (short)f2bf(v[j] - bf2f(h));
            }
            Ah[rt][q] = hi; Al[rt][q] = lo;
        }
    }

    f32x4 acc[2][3];
    #pragma unroll
    for (int rt = 0; rt < 2; ++rt)
        #pragma unroll
        for (int t = 0; t < 3; ++t)
            acc[rt][t] = (f32x4){0.f, 0.f, 0.f, 0.f};

    #pragma unroll
    for (int t = 0; t < 3; ++t) {
        #pragma unroll
        for (int q = 0; q < 4; ++q) {
            const int off = ((t * 4 + q) * 64 + lane) * 8;
            bf16x8 Bh = *(const bf16x8*)(wsh + off);
            bf16x8 Bl = *(const bf16x8*)(wsl + off);
            #pragma unroll
            for (int rt = 0; rt < 2; ++rt) {
                acc[rt][t] = __builtin_amdgcn_mfma_f32_16x16x32_bf16(Ah[rt][q], Bh, acc[rt][t], 0, 0, 0);
                acc[rt][t] = __builtin_amdgcn_mfma_f32_16x16x32_bf16(Ah[rt][q], Bl, acc[rt][t], 0, 0, 0);
                acc[rt][t] = __builtin_amdgcn_mfma_f32_16x16x32_bf16(Al[rt][q], Bh, acc[rt][t], 0, 0, 0);
            }
        }
    }

    #pragma unroll
    for (int rt = 0; rt < 2; ++rt) {
        int r0 = rowBase + rt * 16 + quad * 4;
        #pragma unroll
        for (int reg = 0; reg < 4; ++reg) {
            int r = r0 + reg;
            if (r >= n) continue;
            __half* gr = G + (size_t)r * 40;
            #pragma unroll
            for (int t = 0; t < 3; ++t) {
                int col = t * 16 + m;
                if (col < 40) gr[col] = __float2half(acc[rt][t][reg]);
            }
        }
    }
}

// 128-dim gather (fp16 in, fp16 out): h1[node] = relu((sum H[src]) * ni + b)
__global__ __launch_bounds__(256) void gather_kernel(
        const __half* __restrict__ H, const int* __restrict__ row_ptr,
        const int* __restrict__ deg, const int* __restrict__ csr_src,
        const float* __restrict__ norm_in, const float* __restrict__ b,
        __half* __restrict__ out, int n) {
    const int tid  = threadIdx.x;
    const int node = blockIdx.x * 8 + (tid >> 5);
    const int c    = (tid & 31) * 4;
    if (node >= n) return;

    const int start = row_ptr[node];
    const int cnt   = deg[node];
    float4 acc = make_float4(0.f, 0.f, 0.f, 0.f);

    int j = 0;
    for (; j + 8 <= cnt; j += 8) {
        int s0 = csr_src[start + j];
        int s1 = csr_src[start + j + 1];
        int s2 = csr_src[start + j + 2];
        int s3 = csr_src[start + j + 3];
        int s4 = csr_src[start + j + 4];
        int s5 = csr_src[start + j + 5];
        int s6 = csr_src[start + j + 6];
        int s7 = csr_src[start + j + 7];
        half4 v0 = *(const half4*)(H + (long long)s0 * 128 + c);
        half4 v1 = *(const half4*)(H + (long long)s1 * 128 + c);
        half4 v2 = *(const half4*)(H + (long long)s2 * 128 + c);
        half4 v3 = *(const half4*)(H + (long long)s3 * 128 + c);
        half4 v4 = *(const half4*)(H + (long long)s4 * 128 + c);
        half4 v5 = *(const half4*)(H + (long long)s5 * 128 + c);
        half4 v6 = *(const half4*)(H + (long long)s6 * 128 + c);
        half4 v7 = *(const half4*)(H + (long long)s7 * 128 + c);
        acc_half4(acc, v0); acc_half4(acc, v1); acc_half4(acc, v2); acc_half4(acc, v3);
        acc_half4(acc, v4); acc_half4(acc, v5); acc_half4(acc, v6); acc_half4(acc, v7);
    }
    for (; j + 4 <= cnt; j += 4) {
        int s0 = csr_src[start + j];
        int s1 = csr_src[start + j + 1];
        int s2 = csr_src[start + j + 2];
        int s3 = csr_src[start + j + 3];
        half4 v0 = *(const half4*)(H + (long long)s0 * 128 + c);
        half4 v1 = *(const half4*)(H + (long long)s1 * 128 + c);
        half4 v2 = *(const half4*)(H + (long long)s2 * 128 + c);
        half4 v3 = *(const half4*)(H + (long long)s3 * 128 + c);
        acc_half4(acc, v0); acc_half4(acc, v1); acc_half4(acc, v2); acc_half4(acc, v3);
    }
    for (; j < cnt; ++j) {
        int s0 = csr_src[start + j];
        half4 v0 = *(const half4*)(H + (long long)s0 * 128 + c);
        acc_half4(acc, v0);
    }

    float ni = norm_in[node];
    float4 bb = *(const float4*)(b + c);
    half4 o;
    o.x = __float2half(fmaxf(acc.x * ni + bb.x, 0.f));
    o.y = __float2half(fmaxf(acc.y * ni + bb.y, 0.f));
    o.z = __float2half(fmaxf(acc.z * ni + bb.z, 0.f));
    o.w = __float2half(fmaxf(acc.w * ni + bb.w, 0.f));
    *(half4*)(out + (long long)node * 128 + c) = o;
}

// 40-dim gather (fp16 in, fp32 out): out[node] = (sum G[src]) * ni + b2p
__global__ __launch_bounds__(256) void gather40_kernel(
        const __half* __restrict__ G, const int* __restrict__ row_ptr,
        const int* __restrict__ deg, const int* __restrict__ csr_src,
        const float* __restrict__ norm_in, const float* __restrict__ b2p,
        float* __restrict__ out, int n) {
    const int t = blockIdx.x * 256 + threadIdx.x;
    if (t >= n * 10) return;
    const int node = t / 10;
    const int c    = (t - node * 10) * 4;

    const int start = row_ptr[node];
    const int cnt   = deg[node];
    float4 acc = make_float4(0.f, 0.f, 0.f, 0.f);

    int j = 0;
    for (; j + 8 <= cnt; j += 8) {
        int s0 = csr_src[start + j];
        int s1 = csr_src[start + j + 1];
        int s2 = csr_src[start + j + 2];
        int s3 = csr_src[start + j + 3];
        int s4 = csr_src[start + j + 4];
        int s5 = csr_src[start + j + 5];
        int s6 = csr_src[start + j + 6];
        int s7 = csr_src[start + j + 7];
        half4 v0 = *(const half4*)(G + (long long)s0 * 40 + c);
        half4 v1 = *(const half4*)(G + (long long)s1 * 40 + c);
        half4 v2 = *(const half4*)(G + (long long)s2 * 40 + c);
        half4 v3 = *(const half4*)(G + (long long)s3 * 40 + c);
        half4 v4 = *(const half4*)(G + (long long)s4 * 40 + c);
        half4 v5 = *(const half4*)(G + (long long)s5 * 40 + c);
        half4 v6 = *(const half4*)(G + (long long)s6 * 40 + c);
        half4 v7 = *(const half4*)(G + (long long)s7 * 40 + c);
        acc_half4(acc, v0); acc_half4(acc, v1); acc_half4(acc, v2); acc_half4(acc, v3);
        acc_half4(acc, v4); acc_half4(acc, v5); acc_half4(acc, v6); acc_half4(acc, v7);
    }
    for (; j + 4 <= cnt; j += 4) {
        int s0 = csr_src[start + j];
        int s1 = csr_src[start + j + 1];
        int s2 = csr_src[start + j + 2];
        int s3 = csr_src[start + j + 3];
        half4 v0 = *(const half4*)(G + (long long)s0 * 40 + c);
        half4 v1 = *(const half4*)(G + (long long)s1 * 40 + c);
        half4 v2 = *(const half4*)(G + (long long)s2 * 40 + c);
        half4 v3 = *(const half4*)(G + (long long)s3 * 40 + c);
        acc_half4(acc, v0); acc_half4(acc, v1); acc_half4(acc, v2); acc_half4(acc, v3);
    }
    for (; j < cnt; ++j) {
        int s0 = csr_src[start + j];
        half4 v0 = *(const half4*)(G + (long long)s0 * 40 + c);
        acc_half4(acc, v0);
    }

    float ni = norm_in[node];
    float4 bb = *(const float4*)(b2p + c);
    acc.x = acc.x * ni + bb.x;
    acc.y = acc.y * ni + bb.y;
    acc.z = acc.z * ni + bb.z;
    acc.w = acc.w * ni + bb.w;
    *(float4*)(out + (long long)node * 40 + c) = acc;
}

extern "C" void kernel_launch(void* const* d_in, const int* in_sizes, int n_in,
                              void* d_out, int out_size, void* d_ws, size_t ws_size,
                              hipStream_t stream) {
    const float* x   = (const float*)d_in[0];
    const int*   ei  = (const int*)  d_in[1];
    const float* W1  = (const float*)d_in[2];
    const float* b1  = (const float*)d_in[3];
    const float* W2  = (const float*)d_in[4];
    const float* b2  = (const float*)d_in[5];
    const float* Wfc = (const float*)d_in[6];
    const float* bfc = (const float*)d_in[7];
    float* out = (float*)d_out;

    const int N = in_sizes[0] / 128;
    const int E = in_sizes[1] / 2;
    const int* src = ei;
    const int* dst = ei + E;

    const int B1 = (E + CHUNK - 1) / CHUNK;            // coarse blocks (391)
    const int n_counts = 2 * NB * B1;                   // 200192
    const int n_scan_blocks = (n_counts + SCAN_BLK - 1) / SCAN_BLK;

    char* p = (char*)d_ws;
    float* norm_out = (float*)p; p += (size_t)N * 4;
    float* norm_in  = (float*)p; p += (size_t)N * 4;
    float* bufA     = (float*)p; p += (size_t)N * 128 * 4;   // h1pre fp16, then G fp16
    float* bufB     = (float*)p; p += (size_t)N * 128 * 4;   // h1 fp16 (aliased early: partitions)
    int*   deg_in   = (int*)p;   p += (size_t)N * 4;
    int*   row_ptr  = (int*)p;   p += (size_t)N * 4;
    int*   csr_src  = (int*)p;   p += (size_t)E * 4;
    int*   counts   = (int*)p;   p += (size_t)n_counts * 4;
    int*   coff     = (int*)p;   p += (size_t)n_counts * 4;
    int*   aux      = (int*)p;   p += (size_t)((n_scan_blocks + 3) & ~3) * 4;
    float* W2p      = (float*)p; p += (size_t)128 * 40 * 4;
    float* b2p      = (float*)p; p += (size_t)64 * 4;

    // partition buffers alias bufB (consumed before gather writes h1 there)
    unsigned int*   ppack  = (unsigned int*)bufB;               // E x u32
    unsigned short* es_loc = (unsigned short*)(ppack + E);      // E x u16

    __half* h1pre = (__half*)bufA;   // N x 128 fp16
    __half* G     = (__half*)bufA;   // N x 40  fp16 (reused after gather1)
    __half* h1    = (__half*)bufB;   // N x 128 fp16

    const int T = 256;

    // ---- CSR build + norms: zero per-edge global atomics ----
    count_coarse_kernel<<<B1, T, 0, stream>>>(src, dst, counts, E, B1);
    scan_block_kernel<<<n_scan_blocks, T, 0, stream>>>(counts, coff, aux, n_counts);
    scan_aux_kernel<<<1, 1024, 0, stream>>>(aux, n_scan_blocks);
    add_offsets_kernel<<<(n_counts + T - 1) / T, T, 0, stream>>>(coff, aux, n_counts);
    scatter_coarse_kernel<<<B1, T, 0, stream>>>(src, dst, coff, ppack, es_loc, E, B1);
    fine_dst_kernel<<<NB, T, 0, stream>>>(ppack, coff, deg_in, norm_in,
                                          row_ptr, csr_src, N, B1);
    fine_src_kernel<<<NB, T, 0, stream>>>(es_loc, coff, norm_out, N, E, B1);

    // fold layer2+FC weights
    fold_w2_kernel<<<(129 * 40 + T - 1) / T, T, 0, stream>>>(W2, Wfc, b2, bfc, W2p, b2p);

    // layer 0: h1 = relu(gather(Xn @ W1) * ni + b1)   [MFMA bf16-split GEMM]
    const int gemm_grid = (N + 127) / 128;
    gemm128<<<gemm_grid, T, 0, stream>>>(x, norm_out, W1, h1pre, N);
    const int gather_grid = (N + 7) / 8;
    gather_kernel<<<gather_grid, T, 0, stream>>>(h1pre, row_ptr, deg_in, csr_src,
                                                 norm_in, b1, h1, N);
    // layer 1 + FC fused: out = gather((h1*no) @ W2p) * ni + b2p  [MFMA]
    gemm40<<<gemm_grid, T, 0, stream>>>(h1, norm_out, W2p, G, N);
    gather40_kernel<<<((size_t)N * 10 + T - 1) / T, T, 0, stream>>>(
        G, row_ptr, deg_in, csr_src, norm_in, b2p, out, N);
}

// Round 9
// 323.229 us; speedup vs baseline: 18.3886x; 1.0057x over previous
//
#include <hip/hip_runtime.h>
#include <hip/hip_fp16.h>

// ---------------------------------------------------------------------------
// GCN: 2x GraphConv (norm='both') + FC.  fp32 math, fp16 intermediates.
// R2: CSR gather instead of atomic scatter (5943 -> 840 us).
// R3: LDS-staged fc, gather unroll-4 (840 -> 782 us).
// R4: atomic-free CSR fill (rank trick); fold layer2+FC (782 -> 585 us).
// R5: zero per-edge global atomics: 2-level counting sort (585 -> 503 us).
// R6: fp16 gather intermediates, halved gather bytes (503 -> 423 us).
// R7: MFMA bf16 hi/lo split gemm128; packed partition payloads (423 -> 377).
// R8: MFMA gemm40; h1 stored fp16 (377 -> 325 us).
// R9: (a) reservation-based single-pass partition: per-bucket slabs +
//         one global atomic per (block,bucket) -> count/scan/add kernels
//         deleted (12 -> 9 dispatches, one fewer edge-list pass).
//     (b) gather40 -> 5 lanes x 16B half8 loads (issue-bound on L2 hits).
// gather1 (59 us, 178 MB FETCH @3.5 TB/s from L3) is near its structural
// floor: fp8 breaks the error budget, reuse tiling requires scatter partials.
// ---------------------------------------------------------------------------

#define CHUNK    8192   // edges per partition block
#define NB       256    // coarse buckets (node>>9; ceil(100000/512)=196)
#define SLAB     9216   // per-bucket slab capacity (mean 8192 + 11 sigma)

typedef __attribute__((ext_vector_type(8))) short bf16x8;
typedef __attribute__((ext_vector_type(4))) float f32x4;

struct __align__(8)  half4 { __half x, y, z, w; };
struct __align__(16) half8 { __half h[8]; };

__device__ __forceinline__ void acc_half4(float4& acc, const half4 v) {
    acc.x += __half2float(v.x);
    acc.y += __half2float(v.y);
    acc.z += __half2float(v.z);
    acc.w += __half2float(v.w);
}

__device__ __forceinline__ unsigned short f2bf(float f) {
    union { float f; unsigned u; } v; v.f = f;
    unsigned r = v.u + 0x7FFFu + ((v.u >> 16) & 1u);   // RNE
    return (unsigned short)(r >> 16);
}
__device__ __forceinline__ float bf2f(unsigned short h) {
    union { unsigned u; float f; } v; v.u = ((unsigned)h) << 16;
    return v.f;
}

// cursors start at each bucket's slab base
__global__ void init_cursors_kernel(int* __restrict__ cur_d, int* __restrict__ cur_s,
                                    int nbuck) {
    int i = blockIdx.x * blockDim.x + threadIdx.x;
    if (i < nbuck) { cur_d[i] = i * SLAB; cur_s[i] = i * SLAB; }
}

// ------------- single-pass partition with per-bucket slab reservation -------
// pass 1: LDS histogram of this block's edges per coarse bucket.
// reserve: ONE global atomicAdd per non-empty bucket -> contiguous range.
// pass 2: write edges into the block's private range (coalescing-friendly).
// ppack[i] = (dst_local<<17) | src ; es_loc[i] = src_local (u16).
__global__ __launch_bounds__(256) void scatter_res_kernel(
        const int* __restrict__ src, const int* __restrict__ dst,
        int* __restrict__ cur_d, int* __restrict__ cur_s,
        unsigned int* __restrict__ ppack, unsigned short* __restrict__ es_loc,
        int E) {
    __shared__ int hd[NB], hs[NB], bd[NB], bs[NB];
    const int tid = threadIdx.x;
    hd[tid] = 0; hs[tid] = 0;
    __syncthreads();
    const int base = blockIdx.x * CHUNK;
    const int end  = min(base + CHUNK, E);
    for (int e = base + tid; e < end; e += 256) {
        atomicAdd(&hd[((unsigned)dst[e]) >> 9], 1);
        atomicAdd(&hs[((unsigned)src[e]) >> 9], 1);
    }
    __syncthreads();
    int cd = hd[tid], cs = hs[tid];
    bd[tid] = cd ? atomicAdd(&cur_d[tid], cd) : 0;   // bins >= nbuck have cd==0
    bs[tid] = cs ? atomicAdd(&cur_s[tid], cs) : 0;
    hd[tid] = 0; hs[tid] = 0;
    __syncthreads();
    for (int e = base + tid; e < end; e += 256) {
        int d = dst[e], s = src[e];
        unsigned bin_d = ((unsigned)d) >> 9;
        int pos = bd[bin_d] + atomicAdd(&hd[bin_d], 1);
        ppack[pos] = (((unsigned)d & 511u) << 17) | (unsigned)s;
        unsigned bin_s = ((unsigned)s) >> 9;
        int ps = bs[bin_s] + atomicAdd(&hs[bin_s], 1);
        es_loc[ps] = (unsigned short)(s & 511);
    }
}

// ------------- per-bucket fine pass for dst (slab ranges) -------------------
// Emits deg_in, norm_in, row_ptr (slab-indexed CSR positions) and csr_src.
__global__ __launch_bounds__(256) void fine_dst_kernel(
        const unsigned int* __restrict__ ppack, const int* __restrict__ cur_d,
        int* __restrict__ deg_in, float* __restrict__ norm_in,
        int* __restrict__ row_ptr, int* __restrict__ csr_src, int N_) {
    __shared__ int h[512];
    __shared__ int psum[256];
    const int tid = threadIdx.x;
    const int b = blockIdx.x;
    const int start = b * SLAB;
    const int end   = cur_d[b];
    const int node0 = b * 512;

    h[tid] = 0; h[tid + 256] = 0;
    __syncthreads();
    for (int i = start + tid; i < end; i += 256)
        atomicAdd(&h[ppack[i] >> 17], 1);
    __syncthreads();

    int a0 = h[2 * tid], a1 = h[2 * tid + 1];
    int pair = a0 + a1;
    psum[tid] = pair;
    __syncthreads();
    for (int off = 1; off < 256; off <<= 1) {
        int t = (tid >= off) ? psum[tid - off] : 0;
        __syncthreads();
        psum[tid] += t;
        __syncthreads();
    }
    int base0 = psum[tid] - pair + start;   // slab-local CSR position

    int n0 = node0 + 2 * tid, n1 = n0 + 1;
    if (n0 < N_) {
        deg_in[n0]  = a0;
        row_ptr[n0] = base0;
        norm_in[n0] = rsqrtf((float)(a0 < 1 ? 1 : a0));
    }
    if (n1 < N_) {
        deg_in[n1]  = a1;
        row_ptr[n1] = base0 + a0;
        norm_in[n1] = rsqrtf((float)(a1 < 1 ? 1 : a1));
    }
    h[2 * tid]     = base0;
    h[2 * tid + 1] = base0 + a0;
    __syncthreads();

    for (int i = start + tid; i < end; i += 256) {
        unsigned int pk = ppack[i];
        int pos = atomicAdd(&h[pk >> 17], 1);
        csr_src[pos] = (int)(pk & 0x1FFFFu);
    }
}

// ------------- per-bucket fine pass for src (norm_out only) -----------------
__global__ __launch_bounds__(256) void fine_src_kernel(
        const unsigned short* __restrict__ es_loc, const int* __restrict__ cur_s,
        float* __restrict__ norm_out, int N_) {
    __shared__ int h[512];
    const int tid = threadIdx.x;
    const int b = blockIdx.x;
    const int start = b * SLAB;
    const int end   = cur_s[b];
    const int node0 = b * 512;

    h[tid] = 0; h[tid + 256] = 0;
    __syncthreads();
    for (int i = start + tid; i < end; i += 256)
        atomicAdd(&h[es_loc[i]], 1);
    __syncthreads();

    int n0 = node0 + tid, n1 = n0 + 256;
    if (n0 < N_) { int d = h[tid];       norm_out[n0] = rsqrtf((float)(d < 1 ? 1 : d)); }
    if (n1 < N_) { int d = h[tid + 256]; norm_out[n1] = rsqrtf((float)(d < 1 ? 1 : d)); }
}

// W2p[128x40] = W2[128x128] @ Wfc[128x40];  b2p[40] = b2 @ Wfc + bfc
__global__ void fold_w2_kernel(const float* __restrict__ W2, const float* __restrict__ Wfc,
                               const float* __restrict__ b2, const float* __restrict__ bfc,
                               float* __restrict__ W2p, float* __restrict__ b2p) {
    int idx = blockIdx.x * blockDim.x + threadIdx.x;
    if (idx < 128 * 40) {
        int k = idx / 40, c = idx - (idx / 40) * 40;
        const float* w2row = W2 + k * 128;
        float a = 0.f;
        #pragma unroll 8
        for (int j = 0; j < 128; ++j) a += w2row[j] * Wfc[j * 40 + c];
        W2p[idx] = a;
    } else if (idx < 129 * 40) {
        int c = idx - 128 * 40;
        float a = bfc[c];
        #pragma unroll 8
        for (int j = 0; j < 128; ++j) a += b2[j] * Wfc[j * 40 + c];
        b2p[c] = a;
    }
}

// ---------------------------------------------------------------------------
// Y[nrows x 128] (fp16) = (X * scale[row]) @ W[128x128]  via MFMA bf16 split.
// ---------------------------------------------------------------------------
__global__ __launch_bounds__(256, 2) void gemm128(
        const float* __restrict__ X, const float* __restrict__ scale,
        const float* __restrict__ W, __half* __restrict__ Y, int nrows) {
    __shared__ unsigned short wsh[128 * 128];   // 32 KB, frag-ordered bf16 hi
    __shared__ unsigned short wsl[128 * 128];   // 32 KB, frag-ordered bf16 lo
    const int tid = threadIdx.x;

    for (int i = tid; i < 4096; i += 256) {
        int k  = i >> 5;
        int n0 = (i & 31) * 4;
        float4 wv = *(const float4*)(W + k * 128 + n0);
        int q = k >> 5, j = k & 7, lb = ((k >> 3) & 3) * 16;
        int tcol = n0 >> 4;
        int base = ((tcol * 4 + q) * 64) * 8 + j;
        float vals[4] = {wv.x, wv.y, wv.z, wv.w};
        #pragma unroll
        for (int c = 0; c < 4; ++c) {
            int l = lb + ((n0 + c) & 15);
            unsigned short h = f2bf(vals[c]);
            wsh[base + l * 8] = h;
            wsl[base + l * 8] = f2bf(vals[c] - bf2f(h));
        }
    }
    __syncthreads();

    const int lane = tid & 63;
    const int w    = tid >> 6;
    const int m    = lane & 15;
    const int quad = lane >> 4;
    const int rowBase = blockIdx.x * 128 + w * 32;

    bf16x8 Ah[2][4], Al[2][4];
    #pragma unroll
    for (int rt = 0; rt < 2; ++rt) {
        int r = rowBase + rt * 16 + m;
        float sc = (r < nrows) ? scale[r] : 0.f;
        const float* xr = X + (size_t)(r < nrows ? r : 0) * 128;
        #pragma unroll
        for (int q = 0; q < 4; ++q) {
            int k0 = q * 32 + quad * 8;
            float4 a = *(const float4*)(xr + k0);
            float4 bv = *(const float4*)(xr + k0 + 4);
            float v[8] = {a.x * sc, a.y * sc, a.z * sc, a.w * sc,
                          bv.x * sc, bv.y * sc, bv.z * sc, bv.w * sc};
            bf16x8 hi, lo;
            #pragma unroll
            for (int j = 0; j < 8; ++j) {
                unsigned short h = f2bf(v[j]);
                hi[j] = (short)h;
                lo[j] = (short)f2bf(v[j] - bf2f(h));
            }
            Ah[rt][q] = hi; Al[rt][q] = lo;
        }
    }

    f32x4 acc[2][8];
    #pragma unroll
    for (int rt = 0; rt < 2; ++rt)
        #pragma unroll
        for (int t = 0; t < 8; ++t)
            acc[rt][t] = (f32x4){0.f, 0.f, 0.f, 0.f};

    #pragma unroll
    for (int t = 0; t < 8; ++t) {
        #pragma unroll
        for (int q = 0; q < 4; ++q) {
            const int off = ((t * 4 + q) * 64 + lane) * 8;
            bf16x8 Bh = *(const bf16x8*)(wsh + off);
            bf16x8 Bl = *(const bf16x8*)(wsl + off);
            #pragma unroll
            for (int rt = 0; rt < 2; ++rt) {
                acc[rt][t] = __builtin_amdgcn_mfma_f32_16x16x32_bf16(Ah[rt][q], Bh, acc[rt][t], 0, 0, 0);
                acc[rt][t] = __builtin_amdgcn_mfma_f32_16x16x32_bf16(Ah[rt][q], Bl, acc[rt][t], 0, 0, 0);
                acc[rt][t] = __builtin_amdgcn_mfma_f32_16x16x32_bf16(Al[rt][q], Bh, acc[rt][t], 0, 0, 0);
            }
        }
    }

    #pragma unroll
    for (int rt = 0; rt < 2; ++rt) {
        int r0 = rowBase + rt * 16 + quad * 4;
        #pragma unroll
        for (int reg = 0; reg < 4; ++reg) {
            int r = r0 + reg;
            if (r >= nrows) continue;
            __half* yr = Y + (size_t)r * 128 + m;
            #pragma unroll
            for (int t = 0; t < 8; ++t)
                yr[t * 16] = __float2half(acc[rt][t][reg]);
        }
    }
}

// ---------------------------------------------------------------------------
// G[n x 40] (fp16) = (H[n x 128 fp16] * scale[row]) @ Wp[128 x 40]  via MFMA.
// ---------------------------------------------------------------------------
__global__ __launch_bounds__(256, 2) void gemm40(
        const __half* __restrict__ H, const float* __restrict__ scale,
        const float* __restrict__ Wp, __half* __restrict__ G, int n) {
    __shared__ unsigned short wsh[48 * 128];   // 12 KB, frag-ordered bf16 hi
    __shared__ unsigned short wsl[48 * 128];   // 12 KB, frag-ordered bf16 lo
    const int tid = threadIdx.x;

    for (int i = tid; i < 6144; i += 256) {
        int k  = i / 48;        // 0..127
        int nn = i - k * 48;    // 0..47
        float v = (nn < 40) ? Wp[k * 40 + nn] : 0.f;
        int t = nn >> 4, q = k >> 5, j = k & 7;
        int l = ((k >> 3) & 3) * 16 + (nn & 15);
        int base = ((t * 4 + q) * 64 + l) * 8 + j;
        unsigned short h = f2bf(v);
        wsh[base] = h;
        wsl[base] = f2bf(v - bf2f(h));
    }
    __syncthreads();

    const int lane = tid & 63;
    const int w    = tid >> 6;
    const int m    = lane & 15;
    const int quad = lane >> 4;
    const int rowBase = blockIdx.x * 128 + w * 32;

    bf16x8 Ah[2][4], Al[2][4];
    #pragma unroll
    for (int rt = 0; rt < 2; ++rt) {
        int r = rowBase + rt * 16 + m;
        float sc = (r < n) ? scale[r] : 0.f;
        const __half* xr = H + (size_t)(r < n ? r : 0) * 128;
        #pragma unroll
        for (int q = 0; q < 4; ++q) {
            int k0 = q * 32 + quad * 8;
            half4 a = *(const half4*)(xr + k0);
            half4 bv = *(const half4*)(xr + k0 + 4);
            float v[8] = {__half2float(a.x) * sc, __half2float(a.y) * sc,
                          __half2float(a.z) * sc, __half2float(a.w) * sc,
                          __half2float(bv.x) * sc, __half2float(bv.y) * sc,
                          __half2float(bv.z) * sc, __half2float(bv.w) * sc};
            bf16x8 hi, lo;
            #pragma unroll
            for (int j = 0; j < 8; ++j) {
                unsigned short h = f2bf(v[j]);
                hi[j] = (short)h;
                lo[j] = (short)f2bf(v[j] - bf2f(h));
            }
            Ah[rt][q] = hi; Al[rt][q] = lo;
        }
    }

    f32x4 acc[2][3];
    #pragma unroll
    for (int rt = 0; rt < 2; ++rt)
        #pragma unroll
        for (int t = 0; t < 3; ++t)
            acc[rt][t] = (f32x4){0.f, 0.f, 0.f, 0.f};

    #pragma unroll
    for (int t = 0; t < 3; ++t) {
        #pragma unroll
        for (int q = 0; q < 4; ++q) {
            const int off = ((t * 4 + q) * 64 + lane) * 8;
            bf16x8 Bh = *(const bf16x8*)(wsh + off);
            bf16x8 Bl = *(const bf16x8*)(wsl + off);
            #pragma unroll
            for (int rt = 0; rt < 2; ++rt) {
                acc[rt][t] = __builtin_amdgcn_mfma_f32_16x16x32_bf16(Ah[rt][q], Bh, acc[rt][t], 0, 0, 0);
                acc[rt][t] = __builtin_amdgcn_mfma_f32_16x16x32_bf16(Ah[rt][q], Bl, acc[rt][t], 0, 0, 0);
                acc[rt][t] = __builtin_amdgcn_mfma_f32_16x16x32_bf16(Al[rt][q], Bh, acc[rt][t], 0, 0, 0);
            }
        }
    }

    #pragma unroll
    for (int rt = 0; rt < 2; ++rt) {
        int r0 = rowBase + rt * 16 + quad * 4;
        #pragma unroll
        for (int reg = 0; reg < 4; ++reg) {
            int r = r0 + reg;
            if (r >= n) continue;
            __half* gr = G + (size_t)r * 40;
            #pragma unroll
            for (int t = 0; t < 3; ++t) {
                int col = t * 16 + m;
                if (col < 40) gr[col] = __float2half(acc[rt][t][reg]);
            }
        }
    }
}

// 128-dim gather (fp16 in, fp16 out): h1[node] = relu((sum H[src]) * ni + b)
__global__ __launch_bounds__(256) void gather_kernel(
        const __half* __restrict__ H, const int* __restrict__ row_ptr,
        const int* __restrict__ deg, const int* __restrict__ csr_src,
        const float* __restrict__ norm_in, const float* __restrict__ b,
        __half* __restrict__ out, int n) {
    const int tid  = threadIdx.x;
    const int node = blockIdx.x * 8 + (tid >> 5);
    const int c    = (tid & 31) * 4;
    if (node >= n) return;

    const int start = row_ptr[node];
    const int cnt   = deg[node];
    float4 acc = make_float4(0.f, 0.f, 0.f, 0.f);

    int j = 0;
    for (; j + 8 <= cnt; j += 8) {
        int s0 = csr_src[start + j];
        int s1 = csr_src[start + j + 1];
        int s2 = csr_src[start + j + 2];
        int s3 = csr_src[start + j + 3];
        int s4 = csr_src[start + j + 4];
        int s5 = csr_src[start + j + 5];
        int s6 = csr_src[start + j + 6];
        int s7 = csr_src[start + j + 7];
        half4 v0 = *(const half4*)(H + (long long)s0 * 128 + c);
        half4 v1 = *(const half4*)(H + (long long)s1 * 128 + c);
        half4 v2 = *(const half4*)(H + (long long)s2 * 128 + c);
        half4 v3 = *(const half4*)(H + (long long)s3 * 128 + c);
        half4 v4 = *(const half4*)(H + (long long)s4 * 128 + c);
        half4 v5 = *(const half4*)(H + (long long)s5 * 128 + c);
        half4 v6 = *(const half4*)(H + (long long)s6 * 128 + c);
        half4 v7 = *(const half4*)(H + (long long)s7 * 128 + c);
        acc_half4(acc, v0); acc_half4(acc, v1); acc_half4(acc, v2); acc_half4(acc, v3);
        acc_half4(acc, v4); acc_half4(acc, v5); acc_half4(acc, v6); acc_half4(acc, v7);
    }
    for (; j + 4 <= cnt; j += 4) {
        int s0 = csr_src[start + j];
        int s1 = csr_src[start + j + 1];
        int s2 = csr_src[start + j + 2];
        int s3 = csr_src[start + j + 3];
        half4 v0 = *(const half4*)(H + (long long)s0 * 128 + c);
        half4 v1 = *(const half4*)(H + (long long)s1 * 128 + c);
        half4 v2 = *(const half4*)(H + (long long)s2 * 128 + c);
        half4 v3 = *(const half4*)(H + (long long)s3 * 128 + c);
        acc_half4(acc, v0); acc_half4(acc, v1); acc_half4(acc, v2); acc_half4(acc, v3);
    }
    for (; j < cnt; ++j) {
        int s0 = csr_src[start + j];
        half4 v0 = *(const half4*)(H + (long long)s0 * 128 + c);
        acc_half4(acc, v0);
    }

    float ni = norm_in[node];
    float4 bb = *(const float4*)(b + c);
    half4 o;
    o.x = __float2half(fmaxf(acc.x * ni + bb.x, 0.f));
    o.y = __float2half(fmaxf(acc.y * ni + bb.y, 0.f));
    o.z = __float2half(fmaxf(acc.z * ni + bb.z, 0.f));
    o.w = __float2half(fmaxf(acc.w * ni + bb.w, 0.f));
    *(half4*)(out + (long long)node * 128 + c) = o;
}

// 40-dim gather (fp16 in, fp32 out): out[node] = (sum G[src]) * ni + b2p
// 5 lanes per node, one half8 (16 B) each; G row = 80 B (16B-aligned chunks).
__global__ __launch_bounds__(256) void gather40_kernel(
        const __half* __restrict__ G, const int* __restrict__ row_ptr,
        const int* __restrict__ deg, const int* __restrict__ csr_src,
        const float* __restrict__ norm_in, const float* __restrict__ b2p,
        float* __restrict__ out, int n) {
    const int t = blockIdx.x * 256 + threadIdx.x;
    if (t >= n * 5) return;
    const int node = t / 5;
    const int c    = (t - node * 5) * 8;

    const int start = row_ptr[node];
    const int cnt   = deg[node];
    float acc[8] = {0.f, 0.f, 0.f, 0.f, 0.f, 0.f, 0.f, 0.f};

    int j = 0;
    for (; j + 4 <= cnt; j += 4) {
        int s0 = csr_src[start + j];
        int s1 = csr_src[start + j + 1];
        int s2 = csr_src[start + j + 2];
        int s3 = csr_src[start + j + 3];
        half8 v0 = *(const half8*)(G + (long long)s0 * 40 + c);
        half8 v1 = *(const half8*)(G + (long long)s1 * 40 + c);
        half8 v2 = *(const half8*)(G + (long long)s2 * 40 + c);
        half8 v3 = *(const half8*)(G + (long long)s3 * 40 + c);
        #pragma unroll
        for (int k = 0; k < 8; ++k)
            acc[k] += (__half2float(v0.h[k]) + __half2float(v1.h[k]))
                    + (__half2float(v2.h[k]) + __half2float(v3.h[k]));
    }
    for (; j < cnt; ++j) {
        int s0 = csr_src[start + j];
        half8 v0 = *(const half8*)(G + (long long)s0 * 40 + c);
        #pragma unroll
        for (int k = 0; k < 8; ++k) acc[k] += __half2float(v0.h[k]);
    }

    float ni = norm_in[node];
    float4 o0, o1;
    o0.x = acc[0] * ni + b2p[c + 0];
    o0.y = acc[1] * ni + b2p[c + 1];
    o0.z = acc[2] * ni + b2p[c + 2];
    o0.w = acc[3] * ni + b2p[c + 3];
    o1.x = acc[4] * ni + b2p[c + 4];
    o1.y = acc[5] * ni + b2p[c + 5];
    o1.z = acc[6] * ni + b2p[c + 6];
    o1.w = acc[7] * ni + b2p[c + 7];
    float* op = out + (long long)node * 40 + c;
    *(float4*)(op)     = o0;
    *(float4*)(op + 4) = o1;
}

extern "C" void kernel_launch(void* const* d_in, const int* in_sizes, int n_in,
                              void* d_out, int out_size, void* d_ws, size_t ws_size,
                              hipStream_t stream) {
    const float* x   = (const float*)d_in[0];
    const int*   ei  = (const int*)  d_in[1];
    const float* W1  = (const float*)d_in[2];
    const float* b1  = (const float*)d_in[3];
    const float* W2  = (const float*)d_in[4];
    const float* b2  = (const float*)d_in[5];
    const float* Wfc = (const float*)d_in[6];
    const float* bfc = (const float*)d_in[7];
    float* out = (float*)d_out;

    const int N = in_sizes[0] / 128;
    const int E = in_sizes[1] / 2;
    const int* src = ei;
    const int* dst = ei + E;

    const int nbuck = (N + 511) >> 9;                  // 196
    const int B1 = (E + CHUNK - 1) / CHUNK;            // 196 partition blocks

    char* p = (char*)d_ws;
    float* norm_out = (float*)p; p += (size_t)N * 4;
    float* norm_in  = (float*)p; p += (size_t)N * 4;
    float* bufA     = (float*)p; p += (size_t)N * 128 * 4;   // h1pre fp16, then G fp16
    float* bufB     = (float*)p; p += (size_t)N * 128 * 4;   // h1 fp16 (early: slabs)
    int*   deg_in   = (int*)p;   p += (size_t)N * 4;
    int*   row_ptr  = (int*)p;   p += (size_t)N * 4;
    int*   csr_src  = (int*)p;   p += (size_t)nbuck * SLAB * 4;   // slab-indexed CSR
    int*   cur_d    = (int*)p;   p += (size_t)1024 * 4;
    int*   cur_s    = (int*)p;   p += (size_t)1024 * 4;
    float* W2p      = (float*)p; p += (size_t)128 * 40 * 4;
    float* b2p      = (float*)p; p += (size_t)64 * 4;

    // partition slabs alias bufB (consumed before gather writes h1 there)
    unsigned int*   ppack  = (unsigned int*)bufB;                      // nbuck*SLAB u32
    unsigned short* es_loc = (unsigned short*)(ppack + (size_t)nbuck * SLAB);  // nbuck*SLAB u16

    __half* h1pre = (__half*)bufA;   // N x 128 fp16
    __half* G     = (__half*)bufA;   // N x 40  fp16 (reused after gather1)
    __half* h1    = (__half*)bufB;   // N x 128 fp16

    const int T = 256;

    // ---- partition + norms: single-pass slab reservation ----
    init_cursors_kernel<<<(nbuck + T - 1) / T, T, 0, stream>>>(cur_d, cur_s, nbuck);
    scatter_res_kernel<<<B1, T, 0, stream>>>(src, dst, cur_d, cur_s, ppack, es_loc, E);
    fine_dst_kernel<<<nbuck, T, 0, stream>>>(ppack, cur_d, deg_in, norm_in,
                                             row_ptr, csr_src, N);
    fine_src_kernel<<<nbuck, T, 0, stream>>>(es_loc, cur_s, norm_out, N);

    // fold layer2+FC weights
    fold_w2_kernel<<<(129 * 40 + T - 1) / T, T, 0, stream>>>(W2, Wfc, b2, bfc, W2p, b2p);

    // layer 0: h1 = relu(gather(Xn @ W1) * ni + b1)   [MFMA bf16-split GEMM]
    const int gemm_grid = (N + 127) / 128;
    gemm128<<<gemm_grid, T, 0, stream>>>(x, norm_out, W1, h1pre, N);
    const int gather_grid = (N + 7) / 8;
    gather_kernel<<<gather_grid, T, 0, stream>>>(h1pre, row_ptr, deg_in, csr_src,
                                                 norm_in, b1, h1, N);
    // layer 1 + FC fused: out = gather((h1*no) @ W2p) * ni + b2p  [MFMA]
    gemm40<<<gemm_grid, T, 0, stream>>>(h1, norm_out, W2p, G, N);
    gather40_kernel<<<((size_t)N * 5 + T - 1) / T, T, 0, stream>>>(
        G, row_ptr, deg_in, csr_src, norm_in, b2p, out, N);
}